// Round 1
// baseline (7859.354 us; speedup 1.0000x reference)
//
#include <hip/hip_runtime.h>
#include <hip/hip_bf16.h>

// Problem constants (B=8, N=64, T=128, D=512, H=8, Dh=64)
#define BN   512        // B*N
#define TT   128        // T
#define DD   512        // D
#define HH   8          // heads
#define DH   64         // head dim
#define MTOT (BN * TT)  // 65536 rows

// ---------------------------------------------------------------------------
// gemm3: C[z] = X @ W[z] + b[z], M=65536, N=512, K=512.
// 128x128 tile, BK=32, 256 threads, 8x8 micro-tile.
// A-tile stored TRANSPOSED in LDS so both operand reads are ds_read_b128.
// grid: (mtiles=512, ntiles=4, nweights)
// ---------------------------------------------------------------------------
__global__ __launch_bounds__(256)
void gemm3(const float* __restrict__ X,
           const float* __restrict__ W0, const float* __restrict__ W1,
           const float* __restrict__ W2,
           const float* __restrict__ b0, const float* __restrict__ b1,
           const float* __restrict__ b2,
           float* __restrict__ C0, float* __restrict__ C1,
           float* __restrict__ C2) {
    __shared__ float Xs[32][132];   // [k][m] transposed, pad->16B-aligned rows
    __shared__ float Ws[32][132];   // [k][n]

    const int mt = blockIdx.x;      // 0..511
    const int nt = blockIdx.y;      // 0..3
    const int wz = blockIdx.z;      // 0..2

    const float* W = (wz == 0) ? W0 : (wz == 1) ? W1 : W2;
    const float* bias = (wz == 0) ? b0 : (wz == 1) ? b1 : b2;
    float* C = (wz == 0) ? C0 : (wz == 1) ? C1 : C2;

    const int tid = threadIdx.x;
    const int tc = tid & 15;        // 0..15 -> col group
    const int tr = tid >> 4;        // 0..15 -> row group

    const int m0 = mt * 128;
    const int n0 = nt * 128;

    float bb[8];
#pragma unroll
    for (int j = 0; j < 8; ++j) bb[j] = bias[n0 + tc * 8 + j];

    float acc[8][8];
#pragma unroll
    for (int i = 0; i < 8; ++i)
#pragma unroll
        for (int j = 0; j < 8; ++j) acc[i][j] = 0.f;

    for (int kt = 0; kt < 16; ++kt) {
        const int k0 = kt * 32;
        __syncthreads();
        // stage X tile transposed: 128 rows x 32 cols
#pragma unroll
        for (int it = 0; it < 4; ++it) {
            int idx = tid + it * 256;      // 0..1023 float4 units
            int r = idx >> 3;              // 0..127
            int c4 = idx & 7;              // 0..7
            const float4 v = *(const float4*)(X + (size_t)(m0 + r) * DD + k0 + c4 * 4);
            Xs[c4 * 4 + 0][r] = v.x;
            Xs[c4 * 4 + 1][r] = v.y;
            Xs[c4 * 4 + 2][r] = v.z;
            Xs[c4 * 4 + 3][r] = v.w;
        }
        // stage W tile natural: 32 rows x 128 cols
#pragma unroll
        for (int it = 0; it < 4; ++it) {
            int idx = tid + it * 256;
            int kr = idx >> 5;             // 0..31
            int c4 = idx & 31;             // 0..31
            *(float4*)&Ws[kr][c4 * 4] =
                *(const float4*)(W + (size_t)(k0 + kr) * DD + n0 + c4 * 4);
        }
        __syncthreads();

#pragma unroll 4
        for (int kk = 0; kk < 32; ++kk) {
            float4 a0 = *(const float4*)&Xs[kk][tr * 8];
            float4 a1 = *(const float4*)&Xs[kk][tr * 8 + 4];
            float4 bq0 = *(const float4*)&Ws[kk][tc * 8];
            float4 bq1 = *(const float4*)&Ws[kk][tc * 8 + 4];
            float a[8] = {a0.x, a0.y, a0.z, a0.w, a1.x, a1.y, a1.z, a1.w};
            float b[8] = {bq0.x, bq0.y, bq0.z, bq0.w, bq1.x, bq1.y, bq1.z, bq1.w};
#pragma unroll
            for (int i = 0; i < 8; ++i)
#pragma unroll
                for (int j = 0; j < 8; ++j) acc[i][j] += a[i] * b[j];
        }
    }

    // store with bias
#pragma unroll
    for (int i = 0; i < 8; ++i) {
        size_t row = (size_t)(m0 + tr * 8 + i);
        float4 v0, v1;
        v0.x = acc[i][0] + bb[0]; v0.y = acc[i][1] + bb[1];
        v0.z = acc[i][2] + bb[2]; v0.w = acc[i][3] + bb[3];
        v1.x = acc[i][4] + bb[4]; v1.y = acc[i][5] + bb[5];
        v1.z = acc[i][6] + bb[6]; v1.w = acc[i][7] + bb[7];
        *(float4*)(C + row * DD + n0 + tc * 8) = v0;
        *(float4*)(C + row * DD + n0 + tc * 8 + 4) = v1;
    }
}

// ---------------------------------------------------------------------------
// attn: one block per (bn, h). 128 threads, 1 query row per thread.
// Q,K,V stored as [M=BN*T][D=512] (head h occupies cols h*64..h*64+63).
// Flash-style online softmax over 2 K-blocks of 64, chunked by 16 columns so
// every register array is statically indexed.
// ---------------------------------------------------------------------------
__global__ __launch_bounds__(128)
void attn(const float* __restrict__ Q, const float* __restrict__ K,
          const float* __restrict__ V, const float* __restrict__ mask,
          float* __restrict__ O) {
    __shared__ float Ks[64][64];
    __shared__ float Vs[64][64];
    __shared__ float maskS[TT];

    const int bnh = blockIdx.x;     // 0..4095
    const int bn = bnh >> 3;
    const int h = bnh & 7;
    const int tid = threadIdx.x;    // row r = tid

    const float mv = mask[bn * TT + tid];
    maskS[tid] = mv;
    const bool rowvalid = (mv != 0.f);

    // load this thread's Q row (64 floats)
    float q[64];
    const float* qp = Q + ((size_t)bn * TT + tid) * DD + h * DH;
#pragma unroll
    for (int d4 = 0; d4 < 16; ++d4) {
        float4 v = *(const float4*)(qp + d4 * 4);
        q[d4 * 4 + 0] = v.x; q[d4 * 4 + 1] = v.y;
        q[d4 * 4 + 2] = v.z; q[d4 * 4 + 3] = v.w;
    }

    float out[64];
#pragma unroll
    for (int d = 0; d < 64; ++d) out[d] = 0.f;
    float mrun = -1e30f, lrun = 0.f;

    for (int kb = 0; kb < 2; ++kb) {
        __syncthreads();   // protect prev iteration's LDS reads; maskS ready
        // stage K,V block: rows kb*64 .. kb*64+63 of this head
#pragma unroll
        for (int it = 0; it < 8; ++it) {
            int idx = tid + it * 128;       // 0..1023 float4 units
            int kr = idx >> 4;              // 0..63
            int c4 = idx & 15;              // 0..15
            size_t grow = ((size_t)bn * TT + kb * 64 + kr) * DD + h * DH + c4 * 4;
            *(float4*)&Ks[kr][c4 * 4] = *(const float4*)(K + grow);
            *(float4*)&Vs[kr][c4 * 4] = *(const float4*)(V + grow);
        }
        __syncthreads();

        for (int ch = 0; ch < 4; ++ch) {    // 4 chunks of 16 columns
            float s[16];
#pragma unroll
            for (int cc = 0; cc < 16; ++cc) {
                const int c = ch * 16 + cc;
                float accv = 0.f;
#pragma unroll
                for (int d4 = 0; d4 < 16; ++d4) {
                    float4 kv = *(const float4*)&Ks[c][d4 * 4];
                    accv += q[d4 * 4 + 0] * kv.x + q[d4 * 4 + 1] * kv.y +
                            q[d4 * 4 + 2] * kv.z + q[d4 * 4 + 3] * kv.w;
                }
                const bool valid = rowvalid && (maskS[kb * 64 + c] != 0.f);
                s[cc] = valid ? accv * 0.125f : -1e30f;
            }
            float cmax = s[0];
#pragma unroll
            for (int cc = 1; cc < 16; ++cc) cmax = fmaxf(cmax, s[cc]);
            const float mnew = fmaxf(mrun, cmax);
            const float f = __expf(mrun - mnew);   // exp(-huge)->0, exp(0)->1
            float p[16];
            float ls = 0.f;
#pragma unroll
            for (int cc = 0; cc < 16; ++cc) {
                p[cc] = (s[cc] > -1e29f) ? __expf(s[cc] - mnew) : 0.f;
                ls += p[cc];
            }
            lrun = lrun * f + ls;
            mrun = mnew;
#pragma unroll
            for (int d = 0; d < 64; ++d) out[d] *= f;
#pragma unroll
            for (int cc = 0; cc < 16; ++cc) {
                const int k = ch * 16 + cc;
                const float pk = p[cc];
#pragma unroll
                for (int d4 = 0; d4 < 16; ++d4) {
                    float4 vv = *(const float4*)&Vs[k][d4 * 4];
                    out[d4 * 4 + 0] += pk * vv.x;
                    out[d4 * 4 + 1] += pk * vv.y;
                    out[d4 * 4 + 2] += pk * vv.z;
                    out[d4 * 4 + 3] += pk * vv.w;
                }
            }
        }
    }

    const float inv = (lrun > 0.f) ? 1.f / lrun : 0.f;  // also zeroes invalid rows
    float* op = O + ((size_t)bn * TT + tid) * DD + h * DH;
#pragma unroll
    for (int d4 = 0; d4 < 16; ++d4) {
        float4 v;
        v.x = out[d4 * 4 + 0] * inv; v.y = out[d4 * 4 + 1] * inv;
        v.z = out[d4 * 4 + 2] * inv; v.w = out[d4 * 4 + 3] * inv;
        *(float4*)(op + d4 * 4) = v;
    }
}

// ---------------------------------------------------------------------------
// kernel_launch
// inputs: x(0) mask(1) Wq(2) bq(3) Wk(4) bk(5) Wv(6) bv(7) Wo(8) bo(9)
// workspace: Q | K | V | O, each 65536*512 floats (needs 512 MiB total)
// ---------------------------------------------------------------------------
extern "C" void kernel_launch(void* const* d_in, const int* in_sizes, int n_in,
                              void* d_out, int out_size, void* d_ws, size_t ws_size,
                              hipStream_t stream) {
    const float* x    = (const float*)d_in[0];
    const float* mask = (const float*)d_in[1];
    const float* Wq   = (const float*)d_in[2];
    const float* bq   = (const float*)d_in[3];
    const float* Wk   = (const float*)d_in[4];
    const float* bk   = (const float*)d_in[5];
    const float* Wv   = (const float*)d_in[6];
    const float* bv   = (const float*)d_in[7];
    const float* Wo   = (const float*)d_in[8];
    const float* bo   = (const float*)d_in[9];
    float* out = (float*)d_out;

    const size_t elems = (size_t)MTOT * DD;   // 33,554,432
    float* Qb = (float*)d_ws;
    float* Kb = Qb + elems;
    float* Vb = Kb + elems;
    float* Ob = Vb + elems;

    // QKV projections (one X read, three outputs)
    gemm3<<<dim3(512, 4, 3), 256, 0, stream>>>(x, Wq, Wk, Wv, bq, bk, bv,
                                               Qb, Kb, Vb);
    // fused masked attention
    attn<<<dim3(BN * HH), 128, 0, stream>>>(Qb, Kb, Vb, mask, Ob);
    // output projection
    gemm3<<<dim3(512, 4, 1), 256, 0, stream>>>(Ob, Wo, Wo, Wo, bo, bo, bo,
                                               out, out, out);
}

// Round 2
// 2108.472 us; speedup vs baseline: 3.7275x; 3.7275x over previous
//
#include <hip/hip_runtime.h>
#include <hip/hip_bf16.h>

// Problem constants (B=8, N=64, T=128, D=512, H=8, Dh=64)
#define BN   512        // B*N
#define TT   128        // T
#define DD   512        // D
#define HH   8          // heads
#define DH   64         // head dim
#define MTOT (BN * TT)  // 65536 rows

// ---------------------------------------------------------------------------
// gemm3: C[z] = X @ W[z] + b[z], M=65536, N=512, K=512.
// 128x128 tile, BK=32, 256 threads, 8x8 micro-tile. (unchanged from R0 —
// ~82 TF fp32 = 52% of vector peak; MFMA rewrite is a later round)
// ---------------------------------------------------------------------------
__global__ __launch_bounds__(256)
void gemm3(const float* __restrict__ X,
           const float* __restrict__ W0, const float* __restrict__ W1,
           const float* __restrict__ W2,
           const float* __restrict__ b0, const float* __restrict__ b1,
           const float* __restrict__ b2,
           float* __restrict__ C0, float* __restrict__ C1,
           float* __restrict__ C2) {
    __shared__ float Xs[32][132];   // [k][m] transposed
    __shared__ float Ws[32][132];   // [k][n]

    const int mt = blockIdx.x;
    const int nt = blockIdx.y;
    const int wz = blockIdx.z;

    const float* W = (wz == 0) ? W0 : (wz == 1) ? W1 : W2;
    const float* bias = (wz == 0) ? b0 : (wz == 1) ? b1 : b2;
    float* C = (wz == 0) ? C0 : (wz == 1) ? C1 : C2;

    const int tid = threadIdx.x;
    const int tc = tid & 15;
    const int tr = tid >> 4;

    const int m0 = mt * 128;
    const int n0 = nt * 128;

    float bb[8];
#pragma unroll
    for (int j = 0; j < 8; ++j) bb[j] = bias[n0 + tc * 8 + j];

    float acc[8][8];
#pragma unroll
    for (int i = 0; i < 8; ++i)
#pragma unroll
        for (int j = 0; j < 8; ++j) acc[i][j] = 0.f;

    for (int kt = 0; kt < 16; ++kt) {
        const int k0 = kt * 32;
        __syncthreads();
#pragma unroll
        for (int it = 0; it < 4; ++it) {
            int idx = tid + it * 256;
            int r = idx >> 3;
            int c4 = idx & 7;
            const float4 v = *(const float4*)(X + (size_t)(m0 + r) * DD + k0 + c4 * 4);
            Xs[c4 * 4 + 0][r] = v.x;
            Xs[c4 * 4 + 1][r] = v.y;
            Xs[c4 * 4 + 2][r] = v.z;
            Xs[c4 * 4 + 3][r] = v.w;
        }
#pragma unroll
        for (int it = 0; it < 4; ++it) {
            int idx = tid + it * 256;
            int kr = idx >> 5;
            int c4 = idx & 31;
            *(float4*)&Ws[kr][c4 * 4] =
                *(const float4*)(W + (size_t)(k0 + kr) * DD + n0 + c4 * 4);
        }
        __syncthreads();

#pragma unroll 4
        for (int kk = 0; kk < 32; ++kk) {
            float4 a0 = *(const float4*)&Xs[kk][tr * 8];
            float4 a1 = *(const float4*)&Xs[kk][tr * 8 + 4];
            float4 bq0 = *(const float4*)&Ws[kk][tc * 8];
            float4 bq1 = *(const float4*)&Ws[kk][tc * 8 + 4];
            float a[8] = {a0.x, a0.y, a0.z, a0.w, a1.x, a1.y, a1.z, a1.w};
            float b[8] = {bq0.x, bq0.y, bq0.z, bq0.w, bq1.x, bq1.y, bq1.z, bq1.w};
#pragma unroll
            for (int i = 0; i < 8; ++i)
#pragma unroll
                for (int j = 0; j < 8; ++j) acc[i][j] += a[i] * b[j];
        }
    }

#pragma unroll
    for (int i = 0; i < 8; ++i) {
        size_t row = (size_t)(m0 + tr * 8 + i);
        float4 v0, v1;
        v0.x = acc[i][0] + bb[0]; v0.y = acc[i][1] + bb[1];
        v0.z = acc[i][2] + bb[2]; v0.w = acc[i][3] + bb[3];
        v1.x = acc[i][4] + bb[4]; v1.y = acc[i][5] + bb[5];
        v1.z = acc[i][6] + bb[6]; v1.w = acc[i][7] + bb[7];
        *(float4*)(C + row * DD + n0 + tc * 8) = v0;
        *(float4*)(C + row * DD + n0 + tc * 8 + 4) = v1;
    }
}

// ---------------------------------------------------------------------------
// attn: one block per (bn, h), 256 threads. Each Q-row is owned by TWO
// adjacent lanes (half = tid&1, row = tid>>1); each lane keeps 32 of the 64
// head dims in registers (q[32], out[32] -> 64 persistent VGPRs vs 128
// before, which spilled: R0 showed VGPR=256 + 18.2 GB scratch traffic).
// Full QK dot = partial + __shfl_xor(partial, 1) (pair is always in-wave).
// Softmax state (m, l) computed redundantly in both lanes.
// ---------------------------------------------------------------------------
__global__ __launch_bounds__(256)
void attn(const float* __restrict__ Q, const float* __restrict__ K,
          const float* __restrict__ V, const float* __restrict__ mask,
          float* __restrict__ O) {
    __shared__ float Ks[64][64];
    __shared__ float Vs[64][64];
    __shared__ float maskS[TT];

    const int bnh = blockIdx.x;     // 0..4095
    const int bn = bnh >> 3;
    const int h = bnh & 7;
    const int tid = threadIdx.x;    // 0..255
    const int row = tid >> 1;       // 0..127
    const int half = tid & 1;       // 0..1

    if (tid < TT) maskS[tid] = mask[bn * TT + tid];
    const float mv = mask[bn * TT + row];
    const bool rowvalid = (mv != 0.f);

    // this lane's half of the Q row (32 floats)
    float q[32];
    const float* qp = Q + ((size_t)bn * TT + row) * DD + h * DH + half * 32;
#pragma unroll
    for (int d4 = 0; d4 < 8; ++d4) {
        float4 v = *(const float4*)(qp + d4 * 4);
        q[d4 * 4 + 0] = v.x; q[d4 * 4 + 1] = v.y;
        q[d4 * 4 + 2] = v.z; q[d4 * 4 + 3] = v.w;
    }

    float out[32];
#pragma unroll
    for (int d = 0; d < 32; ++d) out[d] = 0.f;
    float mrun = -1e30f, lrun = 0.f;

    for (int kb = 0; kb < 2; ++kb) {
        __syncthreads();   // maskS ready (kb=0); prev LDS reads done (kb=1)
        // stage K,V block: 64 rows x 64 floats each = 1024 float4 per array
#pragma unroll
        for (int it = 0; it < 4; ++it) {
            int idx = tid + it * 256;       // 0..1023
            int kr = idx >> 4;              // 0..63
            int c4 = idx & 15;              // 0..15
            size_t grow = ((size_t)bn * TT + kb * 64 + kr) * DD + h * DH + c4 * 4;
            *(float4*)&Ks[kr][c4 * 4] = *(const float4*)(K + grow);
            *(float4*)&Vs[kr][c4 * 4] = *(const float4*)(V + grow);
        }
        __syncthreads();

        for (int ch = 0; ch < 4; ++ch) {    // 4 chunks of 16 columns
            float s[16];
#pragma unroll
            for (int cc = 0; cc < 16; ++cc) {
                const int c = ch * 16 + cc;
                float part = 0.f;
#pragma unroll
                for (int d4 = 0; d4 < 8; ++d4) {
                    float4 kv = *(const float4*)&Ks[c][half * 32 + d4 * 4];
                    part += q[d4 * 4 + 0] * kv.x + q[d4 * 4 + 1] * kv.y +
                            q[d4 * 4 + 2] * kv.z + q[d4 * 4 + 3] * kv.w;
                }
                const float full = part + __shfl_xor(part, 1);
                const bool valid = rowvalid && (maskS[kb * 64 + c] != 0.f);
                s[cc] = valid ? full * 0.125f : -1e30f;
            }
            float cmax = s[0];
#pragma unroll
            for (int cc = 1; cc < 16; ++cc) cmax = fmaxf(cmax, s[cc]);
            const float mnew = fmaxf(mrun, cmax);
            const float f = __expf(mrun - mnew);   // exp(-huge)->0, exp(0)->1
            float p[16];
            float ls = 0.f;
#pragma unroll
            for (int cc = 0; cc < 16; ++cc) {
                p[cc] = (s[cc] > -1e29f) ? __expf(s[cc] - mnew) : 0.f;
                ls += p[cc];
            }
            lrun = lrun * f + ls;
            mrun = mnew;
#pragma unroll
            for (int d = 0; d < 32; ++d) out[d] *= f;
#pragma unroll
            for (int cc = 0; cc < 16; ++cc) {
                const int k = ch * 16 + cc;
                const float pk = p[cc];
#pragma unroll
                for (int d4 = 0; d4 < 8; ++d4) {
                    float4 vv = *(const float4*)&Vs[k][half * 32 + d4 * 4];
                    out[d4 * 4 + 0] += pk * vv.x;
                    out[d4 * 4 + 1] += pk * vv.y;
                    out[d4 * 4 + 2] += pk * vv.z;
                    out[d4 * 4 + 3] += pk * vv.w;
                }
            }
        }
    }

    const float inv = (lrun > 0.f) ? 1.f / lrun : 0.f;  // zeroes invalid rows
    float* op = O + ((size_t)bn * TT + row) * DD + h * DH + half * 32;
#pragma unroll
    for (int d4 = 0; d4 < 8; ++d4) {
        float4 v;
        v.x = out[d4 * 4 + 0] * inv; v.y = out[d4 * 4 + 1] * inv;
        v.z = out[d4 * 4 + 2] * inv; v.w = out[d4 * 4 + 3] * inv;
        *(float4*)(op + d4 * 4) = v;
    }
}

// ---------------------------------------------------------------------------
// kernel_launch
// inputs: x(0) mask(1) Wq(2) bq(3) Wk(4) bk(5) Wv(6) bv(7) Wo(8) bo(9)
// workspace: Q | K | V | O, each 65536*512 floats (512 MiB total)
// ---------------------------------------------------------------------------
extern "C" void kernel_launch(void* const* d_in, const int* in_sizes, int n_in,
                              void* d_out, int out_size, void* d_ws, size_t ws_size,
                              hipStream_t stream) {
    const float* x    = (const float*)d_in[0];
    const float* mask = (const float*)d_in[1];
    const float* Wq   = (const float*)d_in[2];
    const float* bq   = (const float*)d_in[3];
    const float* Wk   = (const float*)d_in[4];
    const float* bk   = (const float*)d_in[5];
    const float* Wv   = (const float*)d_in[6];
    const float* bv   = (const float*)d_in[7];
    const float* Wo   = (const float*)d_in[8];
    const float* bo   = (const float*)d_in[9];
    float* out = (float*)d_out;

    const size_t elems = (size_t)MTOT * DD;   // 33,554,432
    float* Qb = (float*)d_ws;
    float* Kb = Qb + elems;
    float* Vb = Kb + elems;
    float* Ob = Vb + elems;

    gemm3<<<dim3(512, 4, 3), 256, 0, stream>>>(x, Wq, Wk, Wv, bq, bk, bv,
                                               Qb, Kb, Vb);
    attn<<<dim3(BN * HH), 256, 0, stream>>>(Qb, Kb, Vb, mask, Ob);
    gemm3<<<dim3(512, 4, 1), 256, 0, stream>>>(Ob, Wo, Wo, Wo, bo, bo, bo,
                                               out, out, out);
}

// Round 4
// 1378.746 us; speedup vs baseline: 5.7004x; 1.5293x over previous
//
#include <hip/hip_runtime.h>
#include <hip/hip_bf16.h>

// Problem constants (B=8, N=64, T=128, D=512, H=8, Dh=64)
#define BN   512        // B*N
#define TT   128        // T
#define DD   512        // D
#define HH   8          // heads
#define DH   64         // head dim
#define MTOT (BN * TT)  // 65536 rows
#define KCAT 1536       // concatenated K for split-bf16 GEMM
#define KA   1024       // A storage cols: [Ahi(512) | Alo(512)]
#define WSZ  (512 * KCAT)  // one converted weight: [512 n][1536 k] ushorts

typedef __attribute__((ext_vector_type(8))) short short8v;   // 8 bf16 (4 VGPR)
typedef __attribute__((ext_vector_type(4))) float float4v;   // MFMA acc

__device__ inline void split_bf16(float x, ushort& hi, ushort& lo) {
    __hip_bfloat16 h = __float2bfloat16(x);
    float hf = __bfloat162float(h);
    __hip_bfloat16 l = __float2bfloat16(x - hf);
    hi = *reinterpret_cast<ushort*>(&h);
    lo = *reinterpret_cast<ushort*>(&l);
}

// ---------------------------------------------------------------------------
// cvt_x: X fp32 [MTOT][512] -> Acat bf16-bits [MTOT][1024] = [hi(512)|lo(512)]
// ---------------------------------------------------------------------------
__global__ __launch_bounds__(256)
void cvt_x(const float* __restrict__ X, ushort* __restrict__ A) {
    const size_t total = (size_t)MTOT * DD / 4;   // float4 units
    for (size_t i = (size_t)blockIdx.x * 256 + threadIdx.x; i < total;
         i += (size_t)gridDim.x * 256) {
        size_t e = i * 4;
        size_t m = e >> 9;          // /512
        int k = (int)(e & 511);
        float4 v = *(const float4*)(X + e);
        ushort h0,h1,h2,h3, l0,l1,l2,l3;
        split_bf16(v.x, h0, l0); split_bf16(v.y, h1, l1);
        split_bf16(v.z, h2, l2); split_bf16(v.w, h3, l3);
        *(ushort4*)(A + m * KA + k)       = make_ushort4(h0,h1,h2,h3);
        *(ushort4*)(A + m * KA + 512 + k) = make_ushort4(l0,l1,l2,l3);
    }
}

// ---------------------------------------------------------------------------
// cvt_w: W fp32 [512 k][512 n] -> Bt bf16-bits [512 n][1536 k''],
// rows of k'': [Bhi(0:512) ; Blo(512:1024) ; Bhi(1024:1536)]
// (pairs with A-tile column map [Ahi|Ahi|Alo])
// ---------------------------------------------------------------------------
__global__ __launch_bounds__(256)
void cvt_w(const float* __restrict__ W, ushort* __restrict__ Bt) {
    int idx = blockIdx.x * 256 + threadIdx.x;   // 512*512 threads
    int n = idx >> 9;
    int k = idx & 511;
    float w = W[(size_t)k * DD + n];
    ushort hi, lo; split_bf16(w, hi, lo);
    Bt[(size_t)n * KCAT + k]        = hi;
    Bt[(size_t)n * KCAT + 512 + k]  = lo;
    Bt[(size_t)n * KCAT + 1024 + k] = hi;
}

// ---------------------------------------------------------------------------
// gemm_mfma: C[z] = split_bf16(A) @ split_bf16(W[z]) + b[z]   (fp32 out)
// m97 structure: 128x128 tile, BK=64, 4 waves (2x2 of 64x64),
// mfma_f32_16x16x32_bf16, global_load_lds width 16, linear LDS.
// K'' = 1536 (24 tiles); A-tile column lookup implements [Ahi|Ahi|Alo].
// ---------------------------------------------------------------------------
__global__ __launch_bounds__(256)
void gemm_mfma(const ushort* __restrict__ A,      // [MTOT][KA]
               const ushort* __restrict__ Wcat,   // [z][512][KCAT]
               const float* __restrict__ b0, const float* __restrict__ b1,
               const float* __restrict__ b2,
               float* __restrict__ C0, float* __restrict__ C1,
               float* __restrict__ C2) {
    __shared__ ushort Alds[128 * 64];
    __shared__ ushort Blds[128 * 64];

    const int mt = blockIdx.x, nt = blockIdx.y, wz = blockIdx.z;
    const ushort* Bt = Wcat + (size_t)wz * WSZ;
    const float* bias = (wz == 0) ? b0 : (wz == 1) ? b1 : b2;
    float* C = (wz == 0) ? C0 : (wz == 1) ? C1 : C2;

    const int tid = threadIdx.x;
    const int lane = tid & 63;
    const int wid = tid >> 6;
    const int wr = wid >> 1, wc = wid & 1;      // wave -> 64x64 quadrant
    const int m0 = mt * 128, n0 = nt * 128;

    float4v acc[4][4] = {};   // 16 fragments of 16x16, 64 f32 regs

    for (int kt = 0; kt < 24; ++kt) {
        const int kb = kt * 64;                                   // B col
        const int ka = (kt < 8) ? kt * 64
                     : (kt < 16) ? (kt - 8) * 64
                     : 512 + (kt - 16) * 64;                      // A col
        __syncthreads();   // previous tile's LDS reads complete
#pragma unroll
        for (int r = 0; r < 4; ++r) {
            // unit u covers 16B; wave-uniform LDS base + lane*16 (HW rule)
            const int ubase = r * 256 + wid * 64;
            const int u = ubase + lane;
            const int row = u >> 3, c = u & 7;
            const ushort* gpA = A + (size_t)(m0 + row) * KA + ka + c * 8;
            __builtin_amdgcn_global_load_lds(
                (const __attribute__((address_space(1))) void*)gpA,
                (__attribute__((address_space(3))) void*)(Alds + ubase * 8),
                16, 0, 0);
            const ushort* gpB = Bt + (size_t)(n0 + row) * KCAT + kb + c * 8;
            __builtin_amdgcn_global_load_lds(
                (const __attribute__((address_space(1))) void*)gpB,
                (__attribute__((address_space(3))) void*)(Blds + ubase * 8),
                16, 0, 0);
        }
        __syncthreads();   // compiler drains vmcnt(0) before barrier

#pragma unroll
        for (int ks = 0; ks < 2; ++ks) {
            const int koff = ks * 32 + (lane >> 4) * 8;
            short8v a[4], b[4];
#pragma unroll
            for (int i = 0; i < 4; ++i)
                a[i] = *(const short8v*)(Alds +
                        (size_t)(wr * 64 + i * 16 + (lane & 15)) * 64 + koff);
#pragma unroll
            for (int j = 0; j < 4; ++j)
                b[j] = *(const short8v*)(Blds +
                        (size_t)(wc * 64 + j * 16 + (lane & 15)) * 64 + koff);
#pragma unroll
            for (int i = 0; i < 4; ++i)
#pragma unroll
                for (int j = 0; j < 4; ++j)
                    acc[i][j] = __builtin_amdgcn_mfma_f32_16x16x32_bf16(
                        a[i], b[j], acc[i][j], 0, 0, 0);
        }
    }

    // epilogue: C/D layout col=lane&15, row=(lane>>4)*4+reg  [m89-verified]
    const int cr = (lane >> 4) * 4;
    const int cc0 = lane & 15;
#pragma unroll
    for (int j = 0; j < 4; ++j) {
        const int col = n0 + wc * 64 + j * 16 + cc0;
        const float bv = bias[col];
#pragma unroll
        for (int i = 0; i < 4; ++i) {
            const size_t rbase = (size_t)(m0 + wr * 64 + i * 16 + cr);
#pragma unroll
            for (int rg = 0; rg < 4; ++rg)
                C[(rbase + rg) * DD + col] = acc[i][j][rg] + bv;
        }
    }
}

// ---------------------------------------------------------------------------
// attn: one block per (bn, h), 256 threads, 2 lanes per Q-row (32 dims each;
// avoids the R1 spill). Reads fp32 Q,K,V; writes output in SPLIT-BF16 form
// into Ocat [MTOT][1024] = [hi(512) | lo(512)] so the O-projection GEMM
// consumes it directly.
// ---------------------------------------------------------------------------
__global__ __launch_bounds__(256)
void attn(const float* __restrict__ Q, const float* __restrict__ K,
          const float* __restrict__ V, const float* __restrict__ mask,
          ushort* __restrict__ Ocat) {
    __shared__ float Ks[64][64];
    __shared__ float Vs[64][64];
    __shared__ float maskS[TT];

    const int bnh = blockIdx.x;     // 0..4095
    const int bn = bnh >> 3;
    const int h = bnh & 7;
    const int tid = threadIdx.x;    // 0..255
    const int row = tid >> 1;       // 0..127
    const int half = tid & 1;       // 0..1

    if (tid < TT) maskS[tid] = mask[bn * TT + tid];
    const float mv = mask[bn * TT + row];
    const bool rowvalid = (mv != 0.f);

    float q[32];
    const float* qp = Q + ((size_t)bn * TT + row) * DD + h * DH + half * 32;
#pragma unroll
    for (int d4 = 0; d4 < 8; ++d4) {
        float4 v = *(const float4*)(qp + d4 * 4);
        q[d4 * 4 + 0] = v.x; q[d4 * 4 + 1] = v.y;
        q[d4 * 4 + 2] = v.z; q[d4 * 4 + 3] = v.w;
    }

    float out[32];
#pragma unroll
    for (int d = 0; d < 32; ++d) out[d] = 0.f;
    float mrun = -1e30f, lrun = 0.f;

    for (int kb = 0; kb < 2; ++kb) {
        __syncthreads();
#pragma unroll
        for (int it = 0; it < 4; ++it) {
            int idx = tid + it * 256;
            int kr = idx >> 4;
            int c4 = idx & 15;
            size_t grow = ((size_t)bn * TT + kb * 64 + kr) * DD + h * DH + c4 * 4;
            *(float4*)&Ks[kr][c4 * 4] = *(const float4*)(K + grow);
            *(float4*)&Vs[kr][c4 * 4] = *(const float4*)(V + grow);
        }
        __syncthreads();

        for (int ch = 0; ch < 4; ++ch) {
            float s[16];
#pragma unroll
            for (int cc = 0; cc < 16; ++cc) {
                const int c = ch * 16 + cc;
                float part = 0.f;
#pragma unroll
                for (int d4 = 0; d4 < 8; ++d4) {
                    float4 kv = *(const float4*)&Ks[c][half * 32 + d4 * 4];
                    part += q[d4 * 4 + 0] * kv.x + q[d4 * 4 + 1] * kv.y +
                            q[d4 * 4 + 2] * kv.z + q[d4 * 4 + 3] * kv.w;
                }
                const float full = part + __shfl_xor(part, 1);
                const bool valid = rowvalid && (maskS[kb * 64 + c] != 0.f);
                s[cc] = valid ? full * 0.125f : -1e30f;
            }
            float cmax = s[0];
#pragma unroll
            for (int cc = 1; cc < 16; ++cc) cmax = fmaxf(cmax, s[cc]);
            const float mnew = fmaxf(mrun, cmax);
            const float f = __expf(mrun - mnew);
            float p[16];
            float ls = 0.f;
#pragma unroll
            for (int cc = 0; cc < 16; ++cc) {
                p[cc] = (s[cc] > -1e29f) ? __expf(s[cc] - mnew) : 0.f;
                ls += p[cc];
            }
            lrun = lrun * f + ls;
            mrun = mnew;
#pragma unroll
            for (int d = 0; d < 32; ++d) out[d] *= f;
#pragma unroll
            for (int cc = 0; cc < 16; ++cc) {
                const int k = ch * 16 + cc;
                const float pk = p[cc];
#pragma unroll
                for (int d4 = 0; d4 < 8; ++d4) {
                    float4 vv = *(const float4*)&Vs[k][half * 32 + d4 * 4];
                    out[d4 * 4 + 0] += pk * vv.x;
                    out[d4 * 4 + 1] += pk * vv.y;
                    out[d4 * 4 + 2] += pk * vv.z;
                    out[d4 * 4 + 3] += pk * vv.w;
                }
            }
        }
    }

    const float inv = (lrun > 0.f) ? 1.f / lrun : 0.f;  // zeroes invalid rows
    ushort hibuf[32], lobuf[32];
#pragma unroll
    for (int d = 0; d < 32; ++d)
        split_bf16(out[d] * inv, hibuf[d], lobuf[d]);

    ushort* op = Ocat + ((size_t)bn * TT + row) * KA + h * DH + half * 32;
#pragma unroll
    for (int g = 0; g < 4; ++g) {
        uint4 wh, wl;
        wh.x = hibuf[g*8+0] | ((uint)hibuf[g*8+1] << 16);
        wh.y = hibuf[g*8+2] | ((uint)hibuf[g*8+3] << 16);
        wh.z = hibuf[g*8+4] | ((uint)hibuf[g*8+5] << 16);
        wh.w = hibuf[g*8+6] | ((uint)hibuf[g*8+7] << 16);
        wl.x = lobuf[g*8+0] | ((uint)lobuf[g*8+1] << 16);
        wl.y = lobuf[g*8+2] | ((uint)lobuf[g*8+3] << 16);
        wl.z = lobuf[g*8+4] | ((uint)lobuf[g*8+5] << 16);
        wl.w = lobuf[g*8+6] | ((uint)lobuf[g*8+7] << 16);
        *(uint4*)(op + g * 8)       = wh;
        *(uint4*)(op + 512 + g * 8) = wl;
    }
}

// ---------------------------------------------------------------------------
// kernel_launch
// inputs: x(0) mask(1) Wq(2) bq(3) Wk(4) bk(5) Wv(6) bv(7) Wo(8) bo(9)
//
// Memory plan (R3 crashed: 518 MiB > proven 512 MiB workspace):
//   d_ws (exactly 512 MiB): Acat[128 MiB] | Qb | Kb | Vb (fp32, 128 MiB each)
//   Wcat_q/k/v (4.5 MiB): stashed in d_out — dead until final GEMM, which
//     overwrites all of d_out afterwards.
//   Wcat_o (1.5 MiB): overlays Qb AFTER attn has consumed Q (stream-ordered).
// ---------------------------------------------------------------------------
extern "C" void kernel_launch(void* const* d_in, const int* in_sizes, int n_in,
                              void* d_out, int out_size, void* d_ws, size_t ws_size,
                              hipStream_t stream) {
    const float* x    = (const float*)d_in[0];
    const float* mask = (const float*)d_in[1];
    const float* Wq   = (const float*)d_in[2];
    const float* bq   = (const float*)d_in[3];
    const float* Wk   = (const float*)d_in[4];
    const float* bk   = (const float*)d_in[5];
    const float* Wv   = (const float*)d_in[6];
    const float* bv   = (const float*)d_in[7];
    const float* Wo   = (const float*)d_in[8];
    const float* bo   = (const float*)d_in[9];
    float* out = (float*)d_out;

    ushort* Acat = (ushort*)d_ws;                       // [MTOT][KA] 128 MiB
    float* Qb = (float*)(Acat + (size_t)MTOT * KA);
    float* Kb = Qb + (size_t)MTOT * DD;
    float* Vb = Kb + (size_t)MTOT * DD;

    ushort* WcatQKV = (ushort*)d_out;                   // 3 x 1.5 MiB scratch
    ushort* WcatO   = (ushort*)Qb;                      // 1.5 MiB, after attn

    cvt_x<<<2048, 256, 0, stream>>>(x, Acat);
    cvt_w<<<1024, 256, 0, stream>>>(Wq, WcatQKV + 0 * (size_t)WSZ);
    cvt_w<<<1024, 256, 0, stream>>>(Wk, WcatQKV + 1 * (size_t)WSZ);
    cvt_w<<<1024, 256, 0, stream>>>(Wv, WcatQKV + 2 * (size_t)WSZ);

    // QKV projections (bf16-split MFMA, K''=1536)
    gemm_mfma<<<dim3(512, 4, 3), 256, 0, stream>>>(Acat, WcatQKV, bq, bk, bv,
                                                   Qb, Kb, Vb);
    // fused masked attention; writes split-bf16 Ocat in-place over Acat
    attn<<<dim3(BN * HH), 256, 0, stream>>>(Qb, Kb, Vb, mask, Acat);
    // Wo conversion into now-dead Qb region, then output projection
    cvt_w<<<1024, 256, 0, stream>>>(Wo, WcatO);
    gemm_mfma<<<dim3(512, 4, 1), 256, 0, stream>>>(Acat, WcatO,
                                                   bo, bo, bo, out, out, out);
}

// Round 5
// 1332.348 us; speedup vs baseline: 5.8989x; 1.0348x over previous
//
#include <hip/hip_runtime.h>
#include <hip/hip_bf16.h>

// Problem constants (B=8, N=64, T=128, D=512, H=8, Dh=64)
#define BN   512        // B*N
#define TT   128        // T
#define DD   512        // D
#define HH   8          // heads
#define DH   64         // head dim
#define MTOT (BN * TT)  // 65536 rows
#define KCAT 1536       // concatenated K for split-bf16 GEMM
#define KA   1024       // A storage cols: [Ahi(512) | Alo(512)]
#define WSZ  (512 * KCAT)  // one converted weight: [512 n][1536 k] ushorts

typedef __attribute__((ext_vector_type(8))) short short8v;   // 8 bf16 (4 VGPR)
typedef __attribute__((ext_vector_type(4))) float float4v;   // MFMA acc

__device__ inline void split_bf16(float x, ushort& hi, ushort& lo) {
    __hip_bfloat16 h = __float2bfloat16(x);
    float hf = __bfloat162float(h);
    __hip_bfloat16 l = __float2bfloat16(x - hf);
    hi = *reinterpret_cast<ushort*>(&h);
    lo = *reinterpret_cast<ushort*>(&l);
}

// ---------------------------------------------------------------------------
// cvt_x: X fp32 [MTOT][512] -> Acat bf16-bits [MTOT][1024] = [hi(512)|lo(512)]
// ---------------------------------------------------------------------------
__global__ __launch_bounds__(256)
void cvt_x(const float* __restrict__ X, ushort* __restrict__ A) {
    const size_t total = (size_t)MTOT * DD / 4;   // float4 units
    for (size_t i = (size_t)blockIdx.x * 256 + threadIdx.x; i < total;
         i += (size_t)gridDim.x * 256) {
        size_t e = i * 4;
        size_t m = e >> 9;          // /512
        int k = (int)(e & 511);
        float4 v = *(const float4*)(X + e);
        ushort h0,h1,h2,h3, l0,l1,l2,l3;
        split_bf16(v.x, h0, l0); split_bf16(v.y, h1, l1);
        split_bf16(v.z, h2, l2); split_bf16(v.w, h3, l3);
        *(ushort4*)(A + m * KA + k)       = make_ushort4(h0,h1,h2,h3);
        *(ushort4*)(A + m * KA + 512 + k) = make_ushort4(l0,l1,l2,l3);
    }
}

// ---------------------------------------------------------------------------
// cvt_w: W fp32 [512 k][512 n] -> Bt bf16-bits [512 n][1536 k''],
// rows of k'': [Bhi(0:512) ; Blo(512:1024) ; Bhi(1024:1536)]
// (pairs with A-tile column map [Ahi|Ahi|Alo])
// ---------------------------------------------------------------------------
__global__ __launch_bounds__(256)
void cvt_w(const float* __restrict__ W, ushort* __restrict__ Bt) {
    int idx = blockIdx.x * 256 + threadIdx.x;   // 512*512 threads
    int n = idx >> 9;
    int k = idx & 511;
    float w = W[(size_t)k * DD + n];
    ushort hi, lo; split_bf16(w, hi, lo);
    Bt[(size_t)n * KCAT + k]        = hi;
    Bt[(size_t)n * KCAT + 512 + k]  = lo;
    Bt[(size_t)n * KCAT + 1024 + k] = hi;
}

// ---------------------------------------------------------------------------
// gemm_mfma: C[z] = split_bf16(A) @ split_bf16(W[z]) + b[z]   (fp32 out)
// m97 structure: 128x128 tile, BK=64, 4 waves (2x2 of 64x64),
// mfma_f32_16x16x32_bf16, global_load_lds width 16.
// R4 showed SQ_LDS_BANK_CONFLICT=1.13e8 (~35% of cycles): the ds_read_b128
// at byte row*128 + g*16 is a 16-way conflict (all lanes in a 16-group hit
// bank quad g*4). Fix per rule #21: XOR-swizzle chunk index with (row&7) on
// BOTH the global_load_lds SOURCE address (LDS dest stays linear) and the
// ds_read address. row%8 == (lane&15)%8 for the fragment reads, so the read
// offset is (g ^ (lane&7))*16 bytes -> 8 bank quads x 2-way (free, m136).
// ---------------------------------------------------------------------------
__global__ __launch_bounds__(256)
void gemm_mfma(const ushort* __restrict__ A,      // [MTOT][KA]
               const ushort* __restrict__ Wcat,   // [z][512][KCAT]
               const float* __restrict__ b0, const float* __restrict__ b1,
               const float* __restrict__ b2,
               float* __restrict__ C0, float* __restrict__ C1,
               float* __restrict__ C2) {
    __shared__ ushort Alds[128 * 64];
    __shared__ ushort Blds[128 * 64];

    const int mt = blockIdx.x, nt = blockIdx.y, wz = blockIdx.z;
    const ushort* Bt = Wcat + (size_t)wz * WSZ;
    const float* bias = (wz == 0) ? b0 : (wz == 1) ? b1 : b2;
    float* C = (wz == 0) ? C0 : (wz == 1) ? C1 : C2;

    const int tid = threadIdx.x;
    const int lane = tid & 63;
    const int wid = tid >> 6;
    const int wr = wid >> 1, wc = wid & 1;      // wave -> 64x64 quadrant
    const int m0 = mt * 128, n0 = nt * 128;

    float4v acc[4][4] = {};   // 16 fragments of 16x16, 64 f32 regs

    for (int kt = 0; kt < 24; ++kt) {
        const int kb = kt * 64;                                   // B col
        const int ka = (kt < 8) ? kt * 64
                     : (kt < 16) ? (kt - 8) * 64
                     : 512 + (kt - 16) * 64;                      // A col
        __syncthreads();   // previous tile's LDS reads complete
#pragma unroll
        for (int r = 0; r < 4; ++r) {
            // unit u covers 16B; wave-uniform LDS base + lane*16 (HW rule)
            const int ubase = r * 256 + wid * 64;
            const int u = ubase + lane;
            const int row = u >> 3, c = u & 7;
            const int csrc = c ^ (row & 7);     // pre-swizzled global source
            const ushort* gpA = A + (size_t)(m0 + row) * KA + ka + csrc * 8;
            __builtin_amdgcn_global_load_lds(
                (const __attribute__((address_space(1))) void*)gpA,
                (__attribute__((address_space(3))) void*)(Alds + ubase * 8),
                16, 0, 0);
            const ushort* gpB = Bt + (size_t)(n0 + row) * KCAT + kb + csrc * 8;
            __builtin_amdgcn_global_load_lds(
                (const __attribute__((address_space(1))) void*)gpB,
                (__attribute__((address_space(3))) void*)(Blds + ubase * 8),
                16, 0, 0);
        }
        __syncthreads();   // compiler drains vmcnt(0) before barrier

#pragma unroll
        for (int ks = 0; ks < 2; ++ks) {
            const int g = ks * 4 + (lane >> 4);          // chunk index 0..7
            const int cswz = (g ^ (lane & 7)) * 8;       // swizzled read off
            short8v a[4], b[4];
#pragma unroll
            for (int i = 0; i < 4; ++i)
                a[i] = *(const short8v*)(Alds +
                        (size_t)(wr * 64 + i * 16 + (lane & 15)) * 64 + cswz);
#pragma unroll
            for (int j = 0; j < 4; ++j)
                b[j] = *(const short8v*)(Blds +
                        (size_t)(wc * 64 + j * 16 + (lane & 15)) * 64 + cswz);
#pragma unroll
            for (int i = 0; i < 4; ++i)
#pragma unroll
                for (int j = 0; j < 4; ++j)
                    acc[i][j] = __builtin_amdgcn_mfma_f32_16x16x32_bf16(
                        a[i], b[j], acc[i][j], 0, 0, 0);
        }
    }

    // epilogue: C/D layout col=lane&15, row=(lane>>4)*4+reg  [m89-verified]
    const int cr = (lane >> 4) * 4;
    const int cc0 = lane & 15;
#pragma unroll
    for (int j = 0; j < 4; ++j) {
        const int col = n0 + wc * 64 + j * 16 + cc0;
        const float bv = bias[col];
#pragma unroll
        for (int i = 0; i < 4; ++i) {
            const size_t rbase = (size_t)(m0 + wr * 64 + i * 16 + cr);
#pragma unroll
            for (int rg = 0; rg < 4; ++rg)
                C[(rbase + rg) * DD + col] = acc[i][j][rg] + bv;
        }
    }
}

// ---------------------------------------------------------------------------
// attn: one block per (bn, h), 256 threads, 2 lanes per Q-row (32 dims each;
// avoids the R1 spill). Reads fp32 Q,K,V; writes output in SPLIT-BF16 form
// into Ocat [MTOT][1024] = [hi(512) | lo(512)] so the O-projection GEMM
// consumes it directly.
// ---------------------------------------------------------------------------
__global__ __launch_bounds__(256)
void attn(const float* __restrict__ Q, const float* __restrict__ K,
          const float* __restrict__ V, const float* __restrict__ mask,
          ushort* __restrict__ Ocat) {
    __shared__ float Ks[64][64];
    __shared__ float Vs[64][64];
    __shared__ float maskS[TT];

    const int bnh = blockIdx.x;     // 0..4095
    const int bn = bnh >> 3;
    const int h = bnh & 7;
    const int tid = threadIdx.x;    // 0..255
    const int row = tid >> 1;       // 0..127
    const int half = tid & 1;       // 0..1

    if (tid < TT) maskS[tid] = mask[bn * TT + tid];
    const float mv = mask[bn * TT + row];
    const bool rowvalid = (mv != 0.f);

    float q[32];
    const float* qp = Q + ((size_t)bn * TT + row) * DD + h * DH + half * 32;
#pragma unroll
    for (int d4 = 0; d4 < 8; ++d4) {
        float4 v = *(const float4*)(qp + d4 * 4);
        q[d4 * 4 + 0] = v.x; q[d4 * 4 + 1] = v.y;
        q[d4 * 4 + 2] = v.z; q[d4 * 4 + 3] = v.w;
    }

    float out[32];
#pragma unroll
    for (int d = 0; d < 32; ++d) out[d] = 0.f;
    float mrun = -1e30f, lrun = 0.f;

    for (int kb = 0; kb < 2; ++kb) {
        __syncthreads();
#pragma unroll
        for (int it = 0; it < 4; ++it) {
            int idx = tid + it * 256;
            int kr = idx >> 4;
            int c4 = idx & 15;
            size_t grow = ((size_t)bn * TT + kb * 64 + kr) * DD + h * DH + c4 * 4;
            *(float4*)&Ks[kr][c4 * 4] = *(const float4*)(K + grow);
            *(float4*)&Vs[kr][c4 * 4] = *(const float4*)(V + grow);
        }
        __syncthreads();

        for (int ch = 0; ch < 4; ++ch) {
            float s[16];
#pragma unroll
            for (int cc = 0; cc < 16; ++cc) {
                const int c = ch * 16 + cc;
                float part = 0.f;
#pragma unroll
                for (int d4 = 0; d4 < 8; ++d4) {
                    float4 kv = *(const float4*)&Ks[c][half * 32 + d4 * 4];
                    part += q[d4 * 4 + 0] * kv.x + q[d4 * 4 + 1] * kv.y +
                            q[d4 * 4 + 2] * kv.z + q[d4 * 4 + 3] * kv.w;
                }
                const float full = part + __shfl_xor(part, 1);
                const bool valid = rowvalid && (maskS[kb * 64 + c] != 0.f);
                s[cc] = valid ? full * 0.125f : -1e30f;
            }
            float cmax = s[0];
#pragma unroll
            for (int cc = 1; cc < 16; ++cc) cmax = fmaxf(cmax, s[cc]);
            const float mnew = fmaxf(mrun, cmax);
            const float f = __expf(mrun - mnew);
            float p[16];
            float ls = 0.f;
#pragma unroll
            for (int cc = 0; cc < 16; ++cc) {
                p[cc] = (s[cc] > -1e29f) ? __expf(s[cc] - mnew) : 0.f;
                ls += p[cc];
            }
            lrun = lrun * f + ls;
            mrun = mnew;
#pragma unroll
            for (int d = 0; d < 32; ++d) out[d] *= f;
#pragma unroll
            for (int cc = 0; cc < 16; ++cc) {
                const int k = ch * 16 + cc;
                const float pk = p[cc];
#pragma unroll
                for (int d4 = 0; d4 < 8; ++d4) {
                    float4 vv = *(const float4*)&Vs[k][half * 32 + d4 * 4];
                    out[d4 * 4 + 0] += pk * vv.x;
                    out[d4 * 4 + 1] += pk * vv.y;
                    out[d4 * 4 + 2] += pk * vv.z;
                    out[d4 * 4 + 3] += pk * vv.w;
                }
            }
        }
    }

    const float inv = (lrun > 0.f) ? 1.f / lrun : 0.f;  // zeroes invalid rows
    ushort hibuf[32], lobuf[32];
#pragma unroll
    for (int d = 0; d < 32; ++d)
        split_bf16(out[d] * inv, hibuf[d], lobuf[d]);

    ushort* op = Ocat + ((size_t)bn * TT + row) * KA + h * DH + half * 32;
#pragma unroll
    for (int g = 0; g < 4; ++g) {
        uint4 wh, wl;
        wh.x = hibuf[g*8+0] | ((uint)hibuf[g*8+1] << 16);
        wh.y = hibuf[g*8+2] | ((uint)hibuf[g*8+3] << 16);
        wh.z = hibuf[g*8+4] | ((uint)hibuf[g*8+5] << 16);
        wh.w = hibuf[g*8+6] | ((uint)hibuf[g*8+7] << 16);
        wl.x = lobuf[g*8+0] | ((uint)lobuf[g*8+1] << 16);
        wl.y = lobuf[g*8+2] | ((uint)lobuf[g*8+3] << 16);
        wl.z = lobuf[g*8+4] | ((uint)lobuf[g*8+5] << 16);
        wl.w = lobuf[g*8+6] | ((uint)lobuf[g*8+7] << 16);
        *(uint4*)(op + g * 8)       = wh;
        *(uint4*)(op + 512 + g * 8) = wl;
    }
}

// ---------------------------------------------------------------------------
// kernel_launch
// inputs: x(0) mask(1) Wq(2) bq(3) Wk(4) bk(5) Wv(6) bv(7) Wo(8) bo(9)
//
// Memory plan (proven 512 MiB workspace; R3's 518 MiB overflowed):
//   d_ws (exactly 512 MiB): Acat[128 MiB] | Qb | Kb | Vb (fp32, 128 MiB each)
//   Wcat_q/k/v (4.5 MiB): stashed in d_out — dead until final GEMM, which
//     overwrites all of d_out afterwards.
//   Wcat_o (1.5 MiB): overlays Qb AFTER attn has consumed Q (stream-ordered).
// ---------------------------------------------------------------------------
extern "C" void kernel_launch(void* const* d_in, const int* in_sizes, int n_in,
                              void* d_out, int out_size, void* d_ws, size_t ws_size,
                              hipStream_t stream) {
    const float* x    = (const float*)d_in[0];
    const float* mask = (const float*)d_in[1];
    const float* Wq   = (const float*)d_in[2];
    const float* bq   = (const float*)d_in[3];
    const float* Wk   = (const float*)d_in[4];
    const float* bk   = (const float*)d_in[5];
    const float* Wv   = (const float*)d_in[6];
    const float* bv   = (const float*)d_in[7];
    const float* Wo   = (const float*)d_in[8];
    const float* bo   = (const float*)d_in[9];
    float* out = (float*)d_out;

    ushort* Acat = (ushort*)d_ws;                       // [MTOT][KA] 128 MiB
    float* Qb = (float*)(Acat + (size_t)MTOT * KA);
    float* Kb = Qb + (size_t)MTOT * DD;
    float* Vb = Kb + (size_t)MTOT * DD;

    ushort* WcatQKV = (ushort*)d_out;                   // 3 x 1.5 MiB scratch
    ushort* WcatO   = (ushort*)Qb;                      // 1.5 MiB, after attn

    cvt_x<<<2048, 256, 0, stream>>>(x, Acat);
    cvt_w<<<1024, 256, 0, stream>>>(Wq, WcatQKV + 0 * (size_t)WSZ);
    cvt_w<<<1024, 256, 0, stream>>>(Wk, WcatQKV + 1 * (size_t)WSZ);
    cvt_w<<<1024, 256, 0, stream>>>(Wv, WcatQKV + 2 * (size_t)WSZ);

    // QKV projections (bf16-split MFMA, K''=1536)
    gemm_mfma<<<dim3(512, 4, 3), 256, 0, stream>>>(Acat, WcatQKV, bq, bk, bv,
                                                   Qb, Kb, Vb);
    // fused masked attention; writes split-bf16 Ocat in-place over Acat
    attn<<<dim3(BN * HH), 256, 0, stream>>>(Qb, Kb, Vb, mask, Acat);
    // Wo conversion into now-dead Qb region, then output projection
    cvt_w<<<1024, 256, 0, stream>>>(Wo, WcatO);
    gemm_mfma<<<dim3(512, 4, 1), 256, 0, stream>>>(Acat, WcatO,
                                                   bo, bo, bo, out, out, out);
}

// Round 6
// 1030.126 us; speedup vs baseline: 7.6295x; 1.2934x over previous
//
#include <hip/hip_runtime.h>
#include <hip/hip_bf16.h>

// Problem constants (B=8, N=64, T=128, D=512, H=8, Dh=64)
#define BN   512        // B*N
#define TT   128        // T
#define DD   512        // D
#define HH   8          // heads
#define DH   64         // head dim
#define MTOT (BN * TT)  // 65536 rows
#define KCAT 1536       // concatenated K for split-bf16 GEMM
#define KA   1024       // A storage cols: [Ahi(512) | Alo(512)]
#define WSZ  (512 * KCAT)  // one converted weight: [512 n][1536 k] ushorts

typedef __attribute__((ext_vector_type(8))) short    short8v;  // 8 bf16
typedef __attribute__((ext_vector_type(8))) _Float16 half8v;   // 8 fp16
typedef __attribute__((ext_vector_type(4))) float    float4v;  // MFMA acc

#define AS1 __attribute__((address_space(1)))
#define AS3 __attribute__((address_space(3)))

__device__ inline void split_bf16(float x, ushort& hi, ushort& lo) {
    __hip_bfloat16 h = __float2bfloat16(x);
    float hf = __bfloat162float(h);
    __hip_bfloat16 l = __float2bfloat16(x - hf);
    hi = *reinterpret_cast<ushort*>(&h);
    lo = *reinterpret_cast<ushort*>(&l);
}

// ---------------------------------------------------------------------------
// cvt_x: X fp32 [MTOT][512] -> Acat bf16-bits [MTOT][1024] = [hi(512)|lo(512)]
// ---------------------------------------------------------------------------
__global__ __launch_bounds__(256)
void cvt_x(const float* __restrict__ X, ushort* __restrict__ A) {
    const size_t total = (size_t)MTOT * DD / 4;   // float4 units
    for (size_t i = (size_t)blockIdx.x * 256 + threadIdx.x; i < total;
         i += (size_t)gridDim.x * 256) {
        size_t e = i * 4;
        size_t m = e >> 9;          // /512
        int k = (int)(e & 511);
        float4 v = *(const float4*)(X + e);
        ushort h0,h1,h2,h3, l0,l1,l2,l3;
        split_bf16(v.x, h0, l0); split_bf16(v.y, h1, l1);
        split_bf16(v.z, h2, l2); split_bf16(v.w, h3, l3);
        *(ushort4*)(A + m * KA + k)       = make_ushort4(h0,h1,h2,h3);
        *(ushort4*)(A + m * KA + 512 + k) = make_ushort4(l0,l1,l2,l3);
    }
}

// ---------------------------------------------------------------------------
// cvt_w: W fp32 [512 k][512 n] -> Bt bf16-bits [512 n][1536 k''],
// rows of k'': [Bhi ; Blo ; Bhi]  (pairs with A column map [Ahi|Ahi|Alo])
// ---------------------------------------------------------------------------
__global__ __launch_bounds__(256)
void cvt_w(const float* __restrict__ W, ushort* __restrict__ Bt) {
    int idx = blockIdx.x * 256 + threadIdx.x;   // 512*512 threads
    int n = idx >> 9;
    int k = idx & 511;
    float w = W[(size_t)k * DD + n];
    ushort hi, lo; split_bf16(w, hi, lo);
    Bt[(size_t)n * KCAT + k]        = hi;
    Bt[(size_t)n * KCAT + 512 + k]  = lo;
    Bt[(size_t)n * KCAT + 1024 + k] = hi;
}

// ---------------------------------------------------------------------------
// gemm_mfma<MODE>: C[z] = split_bf16(A) @ split_bf16(W[z]) + b[z]
// MODE 0: fp32 output (final projection).
// MODE 1 (QKV): z0/z1 -> split-bf16 per-head layout [row][h*128 + sel*64 + d]
//               z2    -> fp16 transposed per head: Vt[(bn*8+h)*64+d][t]
// 128x128 tile, BK=64, 4 waves, mfma_16x16x32_bf16, swizzled staging (R5:
// bank conflicts = 0).
// ---------------------------------------------------------------------------
template <int MODE>
__global__ __launch_bounds__(256)
void gemm_mfma(const ushort* __restrict__ A,      // [MTOT][KA]
               const ushort* __restrict__ Wcat,   // [z][512][KCAT]
               const float* __restrict__ b0, const float* __restrict__ b1,
               const float* __restrict__ b2,
               void* __restrict__ O0, void* __restrict__ O1,
               void* __restrict__ O2) {
    __shared__ ushort Alds[128 * 64];
    __shared__ ushort Blds[128 * 64];

    const int mt = blockIdx.x, nt = blockIdx.y, wz = blockIdx.z;
    const ushort* Bt = Wcat + (size_t)wz * WSZ;
    const float* bias = (wz == 0) ? b0 : (wz == 1) ? b1 : b2;

    const int tid = threadIdx.x;
    const int lane = tid & 63;
    const int wid = tid >> 6;
    const int wr = wid >> 1, wc = wid & 1;      // wave -> 64x64 quadrant
    const int m0 = mt * 128, n0 = nt * 128;

    float4v acc[4][4] = {};

    for (int kt = 0; kt < 24; ++kt) {
        const int kb = kt * 64;                                   // B col
        const int ka = (kt < 8) ? kt * 64
                     : (kt < 16) ? (kt - 8) * 64
                     : 512 + (kt - 16) * 64;                      // A col
        __syncthreads();
#pragma unroll
        for (int r = 0; r < 4; ++r) {
            const int ubase = r * 256 + wid * 64;
            const int u = ubase + lane;
            const int row = u >> 3, c = u & 7;
            const int csrc = c ^ (row & 7);     // pre-swizzled global source
            const ushort* gpA = A + (size_t)(m0 + row) * KA + ka + csrc * 8;
            __builtin_amdgcn_global_load_lds(
                (const AS1 void*)gpA, (AS3 void*)(Alds + ubase * 8), 16, 0, 0);
            const ushort* gpB = Bt + (size_t)(n0 + row) * KCAT + kb + csrc * 8;
            __builtin_amdgcn_global_load_lds(
                (const AS1 void*)gpB, (AS3 void*)(Blds + ubase * 8), 16, 0, 0);
        }
        __syncthreads();

#pragma unroll
        for (int ks = 0; ks < 2; ++ks) {
            const int g = ks * 4 + (lane >> 4);          // chunk index 0..7
            const int cswz = (g ^ (lane & 7)) * 8;       // swizzled read off
            short8v a[4], b[4];
#pragma unroll
            for (int i = 0; i < 4; ++i)
                a[i] = *(const short8v*)(Alds +
                        (size_t)(wr * 64 + i * 16 + (lane & 15)) * 64 + cswz);
#pragma unroll
            for (int j = 0; j < 4; ++j)
                b[j] = *(const short8v*)(Blds +
                        (size_t)(wc * 64 + j * 16 + (lane & 15)) * 64 + cswz);
#pragma unroll
            for (int i = 0; i < 4; ++i)
#pragma unroll
                for (int j = 0; j < 4; ++j)
                    acc[i][j] = __builtin_amdgcn_mfma_f32_16x16x32_bf16(
                        a[i], b[j], acc[i][j], 0, 0, 0);
        }
    }

    // epilogue: C/D layout col=lane&15, row=(lane>>4)*4+reg  [m89-verified]
    const int cr = (lane >> 4) * 4;
    const int cc0 = lane & 15;
    if (MODE == 0) {
        float* C = (float*)((wz == 0) ? O0 : (wz == 1) ? O1 : O2);
#pragma unroll
        for (int j = 0; j < 4; ++j) {
            const int col = n0 + wc * 64 + j * 16 + cc0;
            const float bv = bias[col];
#pragma unroll
            for (int i = 0; i < 4; ++i) {
                const size_t rbase = (size_t)(m0 + wr * 64 + i * 16 + cr);
#pragma unroll
                for (int rg = 0; rg < 4; ++rg)
                    C[(rbase + rg) * DD + col] = acc[i][j][rg] + bv;
            }
        }
    } else if (wz < 2) {
        // Q/K: split-bf16 per-head: [row][h*128 + sel*64 + d]
        ushort* Osp = (ushort*)((wz == 0) ? O0 : O1);
#pragma unroll
        for (int j = 0; j < 4; ++j) {
            const int col = n0 + wc * 64 + j * 16 + cc0;
            const int hh = col >> 6, d = col & 63;
            const float bv = bias[col];
#pragma unroll
            for (int i = 0; i < 4; ++i) {
                const size_t rbase = (size_t)(m0 + wr * 64 + i * 16 + cr);
#pragma unroll
                for (int rg = 0; rg < 4; ++rg) {
                    ushort hi, lo;
                    split_bf16(acc[i][j][rg] + bv, hi, lo);
                    Osp[(rbase + rg) * 1024 + hh * 128 + d]      = hi;
                    Osp[(rbase + rg) * 1024 + hh * 128 + 64 + d] = lo;
                }
            }
        }
    } else {
        // V: fp16, transposed per head: Vt[((bn*8+h)*64+d)*128 + t]
        _Float16* Vt = (_Float16*)O2;
        const int bnq = m0 >> 7;
#pragma unroll
        for (int j = 0; j < 4; ++j) {
            const int col = n0 + wc * 64 + j * 16 + cc0;
            const int hh = col >> 6, d = col & 63;
            const float bv = bias[col];
#pragma unroll
            for (int i = 0; i < 4; ++i) {
                const int t0 = wr * 64 + i * 16 + cr;
#pragma unroll
                for (int rg = 0; rg < 4; ++rg)
                    Vt[((size_t)(bnq * 8 + hh) * 64 + d) * 128 + t0 + rg] =
                        (_Float16)(acc[i][j][rg] + bv);
            }
        }
    }
}

// ---------------------------------------------------------------------------
// attn_mfma: one block per (bn,h), 4 waves x 32 q-rows.
// QK^T: 3-term split-bf16 MFMA (QhiKhi + QloKhi + QhiKlo), K staged in LDS
// via swizzled-source global_load_lds; Q fragments register-direct.
// Softmax in-register (8 in-lane frags + shfl_xor over the 16-lane group).
// PV: P->fp16 in LDS (overlays K), V^T fp16 staged in LDS, single-pass
// mfma_16x16x32_f16. Output written split-bf16 (KA layout) for the O-proj.
// LDS 48.5 KB -> 3 blocks/CU.
// ---------------------------------------------------------------------------
__global__ __launch_bounds__(256)
void attn_mfma(const ushort* __restrict__ Qsp, const ushort* __restrict__ Ksp,
               const _Float16* __restrict__ Vt, const float* __restrict__ mask,
               ushort* __restrict__ Ocat) {
    __shared__ ushort Kl[128 * 128];      // K split rows; later P (fp16)
    __shared__ _Float16 Vl[64 * 128];     // V^T rows
    __shared__ float maskS[TT];

    const int bnh = blockIdx.x, bn = bnh >> 3, h = bnh & 7;
    const int tid = threadIdx.x, lane = tid & 63, wid = tid >> 6;
    const int l15 = lane & 15, l16 = lane >> 4;

    if (tid < TT) maskS[tid] = mask[bn * TT + tid];

    // stage K: 128 rows x 16 chunks (16B), source-swizzled, LDS linear
#pragma unroll
    for (int it = 0; it < 8; ++it) {
        const int ubase = it * 256 + wid * 64;
        const int u = ubase + lane;
        const int row = u >> 4, c = u & 15;
        const ushort* gp = Ksp + (size_t)(bn * TT + row) * 1024 + h * 128 +
                           (c ^ (row & 15)) * 8;
        __builtin_amdgcn_global_load_lds(
            (const AS1 void*)gp, (AS3 void*)(Kl + ubase * 8), 16, 0, 0);
    }
    // stage V^T: 64 rows x 16 chunks
#pragma unroll
    for (int it = 0; it < 4; ++it) {
        const int ubase = it * 256 + wid * 64;
        const int u = ubase + lane;
        const int row = u >> 4, c = u & 15;
        const _Float16* gp = Vt + ((size_t)(bn * HH + h) * 64 + row) * 128 +
                             (c ^ (row & 15)) * 8;
        __builtin_amdgcn_global_load_lds(
            (const AS1 void*)gp, (AS3 void*)(Vl + ubase * 8), 16, 0, 0);
    }
    // Q fragments direct to registers: qf[i][sel][ks]
    short8v qf[2][2][2];
#pragma unroll
    for (int i = 0; i < 2; ++i)
#pragma unroll
        for (int sel = 0; sel < 2; ++sel)
#pragma unroll
            for (int ks = 0; ks < 2; ++ks)
                qf[i][sel][ks] = *(const short8v*)(Qsp +
                    (size_t)(bn * TT + wid * 32 + i * 16 + l15) * 1024 +
                    h * 128 + sel * 64 + ks * 32 + l16 * 8);
    __syncthreads();

    // QK^T: S[q 32][kv 128] per wave; frag (i,j), 96 MFMA
    float4v s[2][8] = {};
#pragma unroll
    for (int ks = 0; ks < 2; ++ks) {
#pragma unroll
        for (int j = 0; j < 8; ++j) {
            const int row = j * 16 + l15;            // row&15 == l15
            const int ghi = ks * 4 + l16;
            short8v bhi = *(const short8v*)(Kl + (size_t)row * 128 +
                                            ((ghi ^ l15) * 8));
            s[0][j] = __builtin_amdgcn_mfma_f32_16x16x32_bf16(
                qf[0][0][ks], bhi, s[0][j], 0, 0, 0);
            s[1][j] = __builtin_amdgcn_mfma_f32_16x16x32_bf16(
                qf[1][0][ks], bhi, s[1][j], 0, 0, 0);
            s[0][j] = __builtin_amdgcn_mfma_f32_16x16x32_bf16(
                qf[0][1][ks], bhi, s[0][j], 0, 0, 0);
            s[1][j] = __builtin_amdgcn_mfma_f32_16x16x32_bf16(
                qf[1][1][ks], bhi, s[1][j], 0, 0, 0);
            const int glo = 8 + ks * 4 + l16;
            short8v blo = *(const short8v*)(Kl + (size_t)row * 128 +
                                            ((glo ^ l15) * 8));
            s[0][j] = __builtin_amdgcn_mfma_f32_16x16x32_bf16(
                qf[0][0][ks], blo, s[0][j], 0, 0, 0);
            s[1][j] = __builtin_amdgcn_mfma_f32_16x16x32_bf16(
                qf[1][0][ks], blo, s[1][j], 0, 0, 0);
        }
    }

    // masked softmax, fully in-register. S frag: row=(l16)*4+reg, col=l15+16j
    float lrow[2][4];
#pragma unroll
    for (int i = 0; i < 2; ++i) {
#pragma unroll
        for (int reg = 0; reg < 4; ++reg) {
            const int q = wid * 32 + i * 16 + l16 * 4 + reg;
            const float rv = maskS[q];
            float mx = -1e30f;
#pragma unroll
            for (int j = 0; j < 8; ++j) {
                const bool valid = (rv != 0.f) && (maskS[j * 16 + l15] != 0.f);
                const float sv = valid ? s[i][j][reg] * 0.125f : -1e30f;
                s[i][j][reg] = sv;
                mx = fmaxf(mx, sv);
            }
#pragma unroll
            for (int d = 1; d < 16; d <<= 1) mx = fmaxf(mx, __shfl_xor(mx, d));
            float ls = 0.f;
#pragma unroll
            for (int j = 0; j < 8; ++j) {
                const float sv = s[i][j][reg];
                const float pv = (sv > -1e29f) ? __expf(sv - mx) : 0.f;
                s[i][j][reg] = pv;
                ls += pv;
            }
#pragma unroll
            for (int d = 1; d < 16; d <<= 1) ls += __shfl_xor(ls, d);
            lrow[i][reg] = ls;
        }
    }

    __syncthreads();          // all waves done reading Kl
    // write P (fp16) into Kl, chunk-swizzled for A-operand reads
    _Float16* Pl = (_Float16*)Kl;
#pragma unroll
    for (int i = 0; i < 2; ++i)
#pragma unroll
        for (int j = 0; j < 8; ++j)
#pragma unroll
            for (int reg = 0; reg < 4; ++reg) {
                const int q = wid * 32 + i * 16 + l16 * 4 + reg;
                const int kv = j * 16 + l15;
                const int c = kv >> 3, o = kv & 7;
                Pl[(size_t)q * 128 + ((c ^ (q & 15)) * 8 + o)] =
                    (_Float16)s[i][j][reg];
            }
    __syncthreads();

    // PV: out[q 32][d 64] per wave, K=128 over kv; 32 MFMA (fp16)
    float4v o_[2][4] = {};
#pragma unroll
    for (int ks = 0; ks < 4; ++ks) {
        half8v a[2];
#pragma unroll
        for (int i = 0; i < 2; ++i) {
            const int row = wid * 32 + i * 16 + l15;   // row&15 == l15
            const int g = ks * 4 + l16;
            a[i] = *(const half8v*)(Pl + (size_t)row * 128 + ((g ^ l15) * 8));
        }
#pragma unroll
        for (int j = 0; j < 4; ++j) {
            const int row = j * 16 + l15;              // d row; row&15 == l15
            const int g = ks * 4 + l16;
            half8v bv = *(const half8v*)(Vl + (size_t)row * 128 +
                                         ((g ^ l15) * 8));
#pragma unroll
            for (int i = 0; i < 2; ++i)
                o_[i][j] = __builtin_amdgcn_mfma_f32_16x16x32_f16(
                    a[i], bv, o_[i][j], 0, 0, 0);
        }
    }

    // normalize + split-bf16 store to Ocat (KA layout)
#pragma unroll
    for (int i = 0; i < 2; ++i)
#pragma unroll
        for (int reg = 0; reg < 4; ++reg) {
            const float l = lrow[i][reg];
            const float inv = (l > 0.f) ? 1.f / l : 0.f;
            const size_t grow = (size_t)bn * TT + wid * 32 + i * 16 +
                                l16 * 4 + reg;
#pragma unroll
            for (int j = 0; j < 4; ++j) {
                const int d = j * 16 + l15;
                ushort hi, lo;
                split_bf16(o_[i][j][reg] * inv, hi, lo);
                Ocat[grow * 1024 + h * DH + d]       = hi;
                Ocat[grow * 1024 + 512 + h * DH + d] = lo;
            }
        }
}

// ---------------------------------------------------------------------------
// kernel_launch
// inputs: x(0) mask(1) Wq(2) bq(3) Wk(4) bk(5) Wv(6) bv(7) Wo(8) bo(9)
//
// Workspace (proven 512 MiB): Acat[128] | Qsp[128] | Ksp[128] | Vt[64] MiB.
// Wcat_q/k/v (4.5 MiB) stashed in d_out (dead until final GEMM overwrites).
// Wcat_o overlays Qsp after attn consumed Q. Ocat overlays Acat.
// ---------------------------------------------------------------------------
extern "C" void kernel_launch(void* const* d_in, const int* in_sizes, int n_in,
                              void* d_out, int out_size, void* d_ws, size_t ws_size,
                              hipStream_t stream) {
    const float* x    = (const float*)d_in[0];
    const float* mask = (const float*)d_in[1];
    const float* Wq   = (const float*)d_in[2];
    const float* bq   = (const float*)d_in[3];
    const float* Wk   = (const float*)d_in[4];
    const float* bk   = (const float*)d_in[5];
    const float* Wv   = (const float*)d_in[6];
    const float* bv   = (const float*)d_in[7];
    const float* Wo   = (const float*)d_in[8];
    const float* bo   = (const float*)d_in[9];
    float* out = (float*)d_out;

    ushort* Acat = (ushort*)d_ws;                        // 128 MiB
    ushort* Qsp  = Acat + (size_t)MTOT * KA;             // 128 MiB
    ushort* Ksp  = Qsp  + (size_t)MTOT * KA;             // 128 MiB
    _Float16* Vtb = (_Float16*)(Ksp + (size_t)MTOT * KA);// 64 MiB

    ushort* WcatQKV = (ushort*)d_out;                    // 4.5 MiB scratch
    ushort* WcatO   = Qsp;                               // after attn

    cvt_x<<<2048, 256, 0, stream>>>(x, Acat);
    cvt_w<<<1024, 256, 0, stream>>>(Wq, WcatQKV + 0 * (size_t)WSZ);
    cvt_w<<<1024, 256, 0, stream>>>(Wk, WcatQKV + 1 * (size_t)WSZ);
    cvt_w<<<1024, 256, 0, stream>>>(Wv, WcatQKV + 2 * (size_t)WSZ);

    // QKV projections -> Qsp/Ksp split-bf16 per-head, Vt fp16 transposed
    gemm_mfma<1><<<dim3(512, 4, 3), 256, 0, stream>>>(
        Acat, WcatQKV, bq, bk, bv, Qsp, Ksp, Vtb);
    // fused masked attention (MFMA); writes split-bf16 Ocat over Acat
    attn_mfma<<<dim3(BN * HH), 256, 0, stream>>>(Qsp, Ksp, Vtb, mask, Acat);
    // Wo conversion into now-dead Qsp region, then output projection
    cvt_w<<<1024, 256, 0, stream>>>(Wo, WcatO);
    gemm_mfma<0><<<dim3(512, 4, 1), 256, 0, stream>>>(
        Acat, WcatO, bo, bo, bo, out, out, out);
}

// Round 10
// 601.858 us; speedup vs baseline: 13.0585x; 1.7116x over previous
//
#include <hip/hip_runtime.h>
#include <hip/hip_bf16.h>

// Problem constants (B=8, N=64, T=128, D=512, H=8, Dh=64)
#define BN   512        // B*N
#define TT   128        // T
#define DD   512        // D
#define HH   8          // heads
#define DH   64         // head dim
#define MTOT (BN * TT)  // 65536 rows

typedef __attribute__((ext_vector_type(8))) _Float16 half8v;   // 8 fp16
typedef __attribute__((ext_vector_type(4))) float    float4v;  // MFMA acc

#define AS1 __attribute__((address_space(1)))
#define AS3 __attribute__((address_space(3)))

union Hbits { _Float16 f; ushort u; };

// ---------------------------------------------------------------------------
// cvt_x: X fp32 [MTOT][512] -> fp16 [MTOT][512]
// ---------------------------------------------------------------------------
__global__ __launch_bounds__(256)
void cvt_x(const float* __restrict__ X, _Float16* __restrict__ Xh) {
    const size_t total = (size_t)MTOT * DD / 4;   // float4 units
    for (size_t i = (size_t)blockIdx.x * 256 + threadIdx.x; i < total;
         i += (size_t)gridDim.x * 256) {
        float4 v = *(const float4*)(X + i * 4);
        Hbits h0, h1, h2, h3;
        h0.f = (_Float16)v.x; h1.f = (_Float16)v.y;
        h2.f = (_Float16)v.z; h3.f = (_Float16)v.w;
        *(ushort4*)(Xh + i * 4) = make_ushort4(h0.u, h1.u, h2.u, h3.u);
    }
}

// ---------------------------------------------------------------------------
// cvt_w: W fp32 [512 k][512 n] -> Wh fp16 [512 n][512 k] (transposed)
// ---------------------------------------------------------------------------
__global__ __launch_bounds__(256)
void cvt_w(const float* __restrict__ W, _Float16* __restrict__ Wh) {
    int idx = blockIdx.x * 256 + threadIdx.x;   // 512*512 threads
    int n = idx >> 9;
    int k = idx & 511;
    Wh[(size_t)n * DD + k] = (_Float16)W[(size_t)k * DD + n];
}

// ---------------------------------------------------------------------------
// gemm_mfma<MODE>: C[z] = A(fp16) @ W[z](fp16) + b[z], K=512 (8 tiles).
// MODE 0: fp32 output (final projection).
// MODE 1 (QKV): z0/z1 -> fp16 row-major [row][512] (Q,K)
//               z2    -> fp16 transposed per head: Vt[((bn*8+h)*64+d)*128+t]
// 128x128 tile, BK=64, 4 waves, mfma_16x16x32_f16. Swizzled staging
// (R5-verified: SQ_LDS_BANK_CONFLICT = 0 with this exact pattern).
// ---------------------------------------------------------------------------
template <int MODE>
__global__ __launch_bounds__(256)
void gemm_mfma(const _Float16* __restrict__ A,    // [MTOT][512]
               const _Float16* __restrict__ W0,   // [512 n][512 k]
               const _Float16* __restrict__ W1,
               const _Float16* __restrict__ W2,
               const float* __restrict__ b0, const float* __restrict__ b1,
               const float* __restrict__ b2,
               void* __restrict__ O0, void* __restrict__ O1,
               void* __restrict__ O2) {
    __shared__ _Float16 Alds[128 * 64];
    __shared__ _Float16 Blds[128 * 64];

    const int mt = blockIdx.x, nt = blockIdx.y, wz = blockIdx.z;
    const _Float16* Bt = (wz == 0) ? W0 : (wz == 1) ? W1 : W2;
    const float* bias = (wz == 0) ? b0 : (wz == 1) ? b1 : b2;

    const int tid = threadIdx.x;
    const int lane = tid & 63;
    const int wid = tid >> 6;
    const int wr = wid >> 1, wc = wid & 1;      // wave -> 64x64 quadrant
    const int m0 = mt * 128, n0 = nt * 128;

    float4v acc[4][4] = {};

    for (int kt = 0; kt < 8; ++kt) {
        const int k0 = kt * 64;
        __syncthreads();
#pragma unroll
        for (int r = 0; r < 4; ++r) {
            const int ubase = r * 256 + wid * 64;
            const int u = ubase + lane;
            const int row = u >> 3, c = u & 7;
            const int csrc = c ^ (row & 7);     // pre-swizzled global source
            const _Float16* gpA = A + (size_t)(m0 + row) * DD + k0 + csrc * 8;
            __builtin_amdgcn_global_load_lds(
                (const AS1 void*)gpA, (AS3 void*)(Alds + ubase * 8), 16, 0, 0);
            const _Float16* gpB = Bt + (size_t)(n0 + row) * DD + k0 + csrc * 8;
            __builtin_amdgcn_global_load_lds(
                (const AS1 void*)gpB, (AS3 void*)(Blds + ubase * 8), 16, 0, 0);
        }
        __syncthreads();

#pragma unroll
        for (int ks = 0; ks < 2; ++ks) {
            const int g = ks * 4 + (lane >> 4);          // chunk index 0..7
            const int cswz = (g ^ (lane & 7)) * 8;       // swizzled read off
            half8v a[4], b[4];
#pragma unroll
            for (int i = 0; i < 4; ++i)
                a[i] = *(const half8v*)(Alds +
                        (size_t)(wr * 64 + i * 16 + (lane & 15)) * 64 + cswz);
#pragma unroll
            for (int j = 0; j < 4; ++j)
                b[j] = *(const half8v*)(Blds +
                        (size_t)(wc * 64 + j * 16 + (lane & 15)) * 64 + cswz);
#pragma unroll
            for (int i = 0; i < 4; ++i)
#pragma unroll
                for (int j = 0; j < 4; ++j)
                    acc[i][j] = __builtin_amdgcn_mfma_f32_16x16x32_f16(
                        a[i], b[j], acc[i][j], 0, 0, 0);
        }
    }

    // epilogue: C/D layout col=lane&15, row=(lane>>4)*4+reg  [m89-verified]
    const int cr = (lane >> 4) * 4;
    const int cc0 = lane & 15;
    if (MODE == 0) {
        float* C = (float*)((wz == 0) ? O0 : (wz == 1) ? O1 : O2);
#pragma unroll
        for (int j = 0; j < 4; ++j) {
            const int col = n0 + wc * 64 + j * 16 + cc0;
            const float bv = bias[col];
#pragma unroll
            for (int i = 0; i < 4; ++i) {
                const size_t rbase = (size_t)(m0 + wr * 64 + i * 16 + cr);
#pragma unroll
                for (int rg = 0; rg < 4; ++rg)
                    C[(rbase + rg) * DD + col] = acc[i][j][rg] + bv;
            }
        }
    } else if (wz < 2) {
        // Q/K: fp16 row-major [row][512]
        _Float16* C = (_Float16*)((wz == 0) ? O0 : O1);
#pragma unroll
        for (int j = 0; j < 4; ++j) {
            const int col = n0 + wc * 64 + j * 16 + cc0;
            const float bv = bias[col];
#pragma unroll
            for (int i = 0; i < 4; ++i) {
                const size_t rbase = (size_t)(m0 + wr * 64 + i * 16 + cr);
#pragma unroll
                for (int rg = 0; rg < 4; ++rg)
                    C[(rbase + rg) * DD + col] = (_Float16)(acc[i][j][rg] + bv);
            }
        }
    } else {
        // V: fp16, transposed per head: Vt[((bn*8+h)*64+d)*128 + t]
        _Float16* Vt = (_Float16*)O2;
        const int bnq = m0 >> 7;       // one m-tile == one bn (TT == 128)
#pragma unroll
        for (int j = 0; j < 4; ++j) {
            const int col = n0 + wc * 64 + j * 16 + cc0;
            const int hh = col >> 6, d = col & 63;
            const float bv = bias[col];
#pragma unroll
            for (int i = 0; i < 4; ++i) {
                const int t0 = wr * 64 + i * 16 + cr;   // multiple of 4
                Hbits e0, e1, e2, e3;
                e0.f = (_Float16)(acc[i][j][0] + bv);
                e1.f = (_Float16)(acc[i][j][1] + bv);
                e2.f = (_Float16)(acc[i][j][2] + bv);
                e3.f = (_Float16)(acc[i][j][3] + bv);
                *(ushort4*)(Vt + ((size_t)(bnq * 8 + hh) * 64 + d) * 128 + t0)
                    = make_ushort4(e0.u, e1.u, e2.u, e3.u);
            }
        }
    }
}

// ---------------------------------------------------------------------------
// attn_mfma: one block per (bn,h), 4 waves x 32 q-rows, all-fp16 MFMA.
// QK^T: 32 mfma_16x16x32_f16, K staged in LDS via swizzled-source
// global_load_lds; Q fragments register-direct. Softmax in-register
// (shfl_xor over the 16-lane group). PV: P->fp16 in LDS (overlays K),
// V^T fp16 in LDS, 32 MFMA. Output fp16 row-major for the O-projection.
// ---------------------------------------------------------------------------
__global__ __launch_bounds__(256)
void attn_mfma(const _Float16* __restrict__ Qh, const _Float16* __restrict__ Kh,
               const _Float16* __restrict__ Vt, const float* __restrict__ mask,
               _Float16* __restrict__ Oh) {
    __shared__ _Float16 KP[128 * 128];    // K rows [128][64]; later P [128][128]
    __shared__ _Float16 Vl[64 * 128];     // V^T rows
    __shared__ float maskS[TT];

    const int bnh = blockIdx.x, bn = bnh >> 3, h = bnh & 7;
    const int tid = threadIdx.x, lane = tid & 63, wid = tid >> 6;
    const int l15 = lane & 15, l16 = lane >> 4;

    if (tid < TT) maskS[tid] = mask[bn * TT + tid];

    // stage K: 128 rows x 8 chunks (16B), source-swizzled, LDS linear
#pragma unroll
    for (int it = 0; it < 4; ++it) {
        const int ubase = it * 256 + wid * 64;
        const int u = ubase + lane;
        const int row = u >> 3, c = u & 7;
        const _Float16* gp = Kh + (size_t)(bn * TT + row) * DD + h * DH +
                             (c ^ (row & 7)) * 8;
        __builtin_amdgcn_global_load_lds(
            (const AS1 void*)gp, (AS3 void*)(KP + ubase * 8), 16, 0, 0);
    }
    // stage V^T: 64 rows x 16 chunks
#pragma unroll
    for (int it = 0; it < 4; ++it) {
        const int ubase = it * 256 + wid * 64;
        const int u = ubase + lane;
        const int row = u >> 4, c = u & 15;
        const _Float16* gp = Vt + ((size_t)(bn * HH + h) * 64 + row) * 128 +
                             (c ^ (row & 15)) * 8;
        __builtin_amdgcn_global_load_lds(
            (const AS1 void*)gp, (AS3 void*)(Vl + ubase * 8), 16, 0, 0);
    }
    // Q fragments direct to registers: qf[i][ks]
    half8v qf[2][2];
#pragma unroll
    for (int i = 0; i < 2; ++i)
#pragma unroll
        for (int ks = 0; ks < 2; ++ks)
            qf[i][ks] = *(const half8v*)(Qh +
                (size_t)(bn * TT + wid * 32 + i * 16 + l15) * DD +
                h * DH + ks * 32 + l16 * 8);
    __syncthreads();

    // QK^T: S[q 32][kv 128] per wave; 32 MFMA
    float4v s[2][8] = {};
#pragma unroll
    for (int ks = 0; ks < 2; ++ks) {
#pragma unroll
        for (int j = 0; j < 8; ++j) {
            const int row = j * 16 + l15;            // row&7 == l15&7
            const int g = ks * 4 + l16;
            half8v bf = *(const half8v*)(KP + (size_t)row * 64 +
                                         ((g ^ (l15 & 7)) * 8));
            s[0][j] = __builtin_amdgcn_mfma_f32_16x16x32_f16(
                qf[0][ks], bf, s[0][j], 0, 0, 0);
            s[1][j] = __builtin_amdgcn_mfma_f32_16x16x32_f16(
                qf[1][ks], bf, s[1][j], 0, 0, 0);
        }
    }

    // masked softmax, in-register. S frag: row=l16*4+reg, col=l15+16j
    float lrow[2][4];
#pragma unroll
    for (int i = 0; i < 2; ++i) {
#pragma unroll
        for (int reg = 0; reg < 4; ++reg) {
            const int q = wid * 32 + i * 16 + l16 * 4 + reg;
            const float rv = maskS[q];
            float mx = -1e30f;
#pragma unroll
            for (int j = 0; j < 8; ++j) {
                const bool valid = (rv != 0.f) && (maskS[j * 16 + l15] != 0.f);
                const float sv = valid ? s[i][j][reg] * 0.125f : -1e30f;
                s[i][j][reg] = sv;
                mx = fmaxf(mx, sv);
            }
#pragma unroll
            for (int d = 1; d < 16; d <<= 1) mx = fmaxf(mx, __shfl_xor(mx, d));
            float ls = 0.f;
#pragma unroll
            for (int j = 0; j < 8; ++j) {
                const float sv = s[i][j][reg];
                const float pv = (sv > -1e29f) ? __expf(sv - mx) : 0.f;
                s[i][j][reg] = pv;
                ls += pv;
            }
#pragma unroll
            for (int d = 1; d < 16; d <<= 1) ls += __shfl_xor(ls, d);
            lrow[i][reg] = ls;
        }
    }

    __syncthreads();          // all waves done reading KP (as K)
    // write P (fp16) into KP [128 q][128 kv], chunk-swizzled for A reads
#pragma unroll
    for (int i = 0; i < 2; ++i)
#pragma unroll
        for (int j = 0; j < 8; ++j)
#pragma unroll
            for (int reg = 0; reg < 4; ++reg) {
                const int q = wid * 32 + i * 16 + l16 * 4 + reg;
                const int kv = j * 16 + l15;
                const int c = kv >> 3, o = kv & 7;
                KP[(size_t)q * 128 + ((c ^ (q & 15)) * 8 + o)] =
                    (_Float16)s[i][j][reg];
            }
    __syncthreads();

    // PV: out[q 32][d 64] per wave, K=128 over kv; 32 MFMA
    float4v o_[2][4] = {};
#pragma unroll
    for (int ks = 0; ks < 4; ++ks) {
        half8v a[2];
#pragma unroll
        for (int i = 0; i < 2; ++i) {
            const int row = wid * 32 + i * 16 + l15;   // row&15 == l15
            const int g = ks * 4 + l16;
            a[i] = *(const half8v*)(KP + (size_t)row * 128 + ((g ^ l15) * 8));
        }
#pragma unroll
        for (int j = 0; j < 4; ++j) {
            const int row = j * 16 + l15;              // d row; row&15 == l15
            const int g = ks * 4 + l16;
            half8v bv = *(const half8v*)(Vl + (size_t)row * 128 +
                                         ((g ^ l15) * 8));
#pragma unroll
            for (int i = 0; i < 2; ++i)
                o_[i][j] = __builtin_amdgcn_mfma_f32_16x16x32_f16(
                    a[i], bv, o_[i][j], 0, 0, 0);
        }
    }

    // normalize + fp16 store to Oh [row][512]
#pragma unroll
    for (int i = 0; i < 2; ++i)
#pragma unroll
        for (int reg = 0; reg < 4; ++reg) {
            const float l = lrow[i][reg];
            const float inv = (l > 0.f) ? 1.f / l : 0.f;  // zero invalid rows
            const size_t grow = (size_t)bn * TT + wid * 32 + i * 16 +
                                l16 * 4 + reg;
#pragma unroll
            for (int j = 0; j < 4; ++j) {
                const int d = j * 16 + l15;
                Oh[grow * DD + h * DH + d] = (_Float16)(o_[i][j][reg] * inv);
            }
        }
}

// ---------------------------------------------------------------------------
// kernel_launch
// inputs: x(0) mask(1) Wq(2) bq(3) Wk(4) bk(5) Wv(6) bv(7) Wo(8) bo(9)
//
// Workspace (322 MiB of the proven 512): Xh[64] | Qh[64] | Kh[64] | Vt[64] |
// Oh[64] | Wh0..3 [2 MiB]. All fp16.
// ---------------------------------------------------------------------------
extern "C" void kernel_launch(void* const* d_in, const int* in_sizes, int n_in,
                              void* d_out, int out_size, void* d_ws, size_t ws_size,
                              hipStream_t stream) {
    const float* x    = (const float*)d_in[0];
    const float* mask = (const float*)d_in[1];
    const float* Wq   = (const float*)d_in[2];
    const float* bq   = (const float*)d_in[3];
    const float* Wk   = (const float*)d_in[4];
    const float* bk   = (const float*)d_in[5];
    const float* Wv   = (const float*)d_in[6];
    const float* bv   = (const float*)d_in[7];
    const float* Wo   = (const float*)d_in[8];
    const float* bo   = (const float*)d_in[9];
    float* out = (float*)d_out;

    const size_t elems = (size_t)MTOT * DD;          // 33.5M halves per buffer
    _Float16* Xh  = (_Float16*)d_ws;
    _Float16* Qh  = Xh + elems;
    _Float16* Kh  = Qh + elems;
    _Float16* Vtb = Kh + elems;
    _Float16* Oh  = Vtb + elems;
    _Float16* Wh  = Oh + elems;                      // 4 x 512*512

    cvt_x<<<2048, 256, 0, stream>>>(x, Xh);
    cvt_w<<<1024, 256, 0, stream>>>(Wq, Wh + 0 * (size_t)DD * DD);
    cvt_w<<<1024, 256, 0, stream>>>(Wk, Wh + 1 * (size_t)DD * DD);
    cvt_w<<<1024, 256, 0, stream>>>(Wv, Wh + 2 * (size_t)DD * DD);
    cvt_w<<<1024, 256, 0, stream>>>(Wo, Wh + 3 * (size_t)DD * DD);

    // QKV projections -> Qh/Kh fp16 row-major, Vt fp16 transposed per head
    gemm_mfma<1><<<dim3(512, 4, 3), 256, 0, stream>>>(
        Xh, Wh + 0 * (size_t)DD * DD, Wh + 1 * (size_t)DD * DD,
        Wh + 2 * (size_t)DD * DD, bq, bk, bv, Qh, Kh, Vtb);
    // fused masked attention (all-fp16 MFMA)
    attn_mfma<<<dim3(BN * HH), 256, 0, stream>>>(Qh, Kh, Vtb, mask, Oh);
    // output projection (fp32 out)
    gemm_mfma<0><<<dim3(512, 4, 1), 256, 0, stream>>>(
        Oh, Wh + 3 * (size_t)DD * DD, nullptr, nullptr, bo, bo, bo,
        out, out, out);
}

// Round 11
// 577.725 us; speedup vs baseline: 13.6040x; 1.0418x over previous
//
#include <hip/hip_runtime.h>
#include <hip/hip_bf16.h>

// Problem constants (B=8, N=64, T=128, D=512, H=8, Dh=64)
#define BN   512        // B*N
#define TT   128        // T
#define DD   512        // D
#define HH   8          // heads
#define DH   64         // head dim
#define MTOT (BN * TT)  // 65536 rows

typedef __attribute__((ext_vector_type(8))) _Float16 half8v;   // 8 fp16
typedef __attribute__((ext_vector_type(4))) float    float4v;  // MFMA acc

#define AS1 __attribute__((address_space(1)))
#define AS3 __attribute__((address_space(3)))

union Hbits { _Float16 f; ushort u; };

// ---------------------------------------------------------------------------
// cvt_x: X fp32 [MTOT][512] -> fp16 [MTOT][512]
// ---------------------------------------------------------------------------
__global__ __launch_bounds__(256)
void cvt_x(const float* __restrict__ X, _Float16* __restrict__ Xh) {
    const size_t total = (size_t)MTOT * DD / 4;   // float4 units
    for (size_t i = (size_t)blockIdx.x * 256 + threadIdx.x; i < total;
         i += (size_t)gridDim.x * 256) {
        float4 v = *(const float4*)(X + i * 4);
        Hbits h0, h1, h2, h3;
        h0.f = (_Float16)v.x; h1.f = (_Float16)v.y;
        h2.f = (_Float16)v.z; h3.f = (_Float16)v.w;
        *(ushort4*)(Xh + i * 4) = make_ushort4(h0.u, h1.u, h2.u, h3.u);
    }
}

// ---------------------------------------------------------------------------
// cvt_w4: all four W fp32 [512 k][512 n] -> Wh fp16 [4][512 n][512 k]
// (one launch instead of four)
// ---------------------------------------------------------------------------
__global__ __launch_bounds__(256)
void cvt_w4(const float* __restrict__ W0, const float* __restrict__ W1,
            const float* __restrict__ W2, const float* __restrict__ W3,
            _Float16* __restrict__ Wh) {
    const int z = blockIdx.y;
    const float* W = (z == 0) ? W0 : (z == 1) ? W1 : (z == 2) ? W2 : W3;
    _Float16* dst = Wh + (size_t)z * DD * DD;
    int idx = blockIdx.x * 256 + threadIdx.x;   // 512*512 threads over x
    int n = idx >> 9;
    int k = idx & 511;
    dst[(size_t)n * DD + k] = (_Float16)W[(size_t)k * DD + n];
}

// ---------------------------------------------------------------------------
// gemm_mfma<MODE>: C[z] = A(fp16) @ W[z](fp16) + b[z], K=512 (8 tiles).
// MODE 0: fp32 output (final projection), grid = 512*4 (mt-major).
// MODE 1 (QKV): grid = 512*12, bid = mt*12 + wz*4 + nt so the 12 blocks
//   sharing one A-panel are dispatch-adjacent (R10: FETCH=399MB ~6x A
//   over-fetch from mt-fastest ordering).
// 2-phase double-buffered K-loop (T3-minimum): STAGE(kt+1) issued BEFORE
// compute(kt), one vmcnt-drain barrier per K-step (R10: MfmaUtil=24%,
// stage+barrier serialization was the stall). LDS 64 KB -> 2 blocks/CU.
// Swizzled staging (R5-verified: SQ_LDS_BANK_CONFLICT = 0).
// ---------------------------------------------------------------------------
template <int MODE>
__global__ __launch_bounds__(256)
void gemm_mfma(const _Float16* __restrict__ A,    // [MTOT][512]
               const _Float16* __restrict__ W0,   // [512 n][512 k]
               const _Float16* __restrict__ W1,
               const _Float16* __restrict__ W2,
               const float* __restrict__ b0, const float* __restrict__ b1,
               const float* __restrict__ b2,
               void* __restrict__ O0, void* __restrict__ O1,
               void* __restrict__ O2) {
    __shared__ _Float16 Alds[2][128 * 64];
    __shared__ _Float16 Blds[2][128 * 64];

    const int bid = blockIdx.x;
    int mt, nt, wz;
    if (MODE == 1) {
        mt = bid / 12;
        const int r = bid - mt * 12;
        wz = r >> 2;
        nt = r & 3;
    } else {
        mt = bid >> 2;
        nt = bid & 3;
        wz = 0;
    }
    const _Float16* Bt = (wz == 0) ? W0 : (wz == 1) ? W1 : W2;
    const float* bias = (wz == 0) ? b0 : (wz == 1) ? b1 : b2;

    const int tid = threadIdx.x;
    const int lane = tid & 63;
    const int wid = tid >> 6;
    const int wr = wid >> 1, wc = wid & 1;      // wave -> 64x64 quadrant
    const int m0 = mt * 128, n0 = nt * 128;

    auto STAGE = [&](int kt, int buf) {
#pragma unroll
        for (int r = 0; r < 4; ++r) {
            const int ubase = r * 256 + wid * 64;
            const int u = ubase + lane;
            const int row = u >> 3, c = u & 7;
            const int csrc = c ^ (row & 7);     // pre-swizzled global source
            const _Float16* gpA = A + (size_t)(m0 + row) * DD + kt * 64 + csrc * 8;
            __builtin_amdgcn_global_load_lds(
                (const AS1 void*)gpA, (AS3 void*)(&Alds[buf][ubase * 8]),
                16, 0, 0);
            const _Float16* gpB = Bt + (size_t)(n0 + row) * DD + kt * 64 + csrc * 8;
            __builtin_amdgcn_global_load_lds(
                (const AS1 void*)gpB, (AS3 void*)(&Blds[buf][ubase * 8]),
                16, 0, 0);
        }
    };

    float4v acc[4][4] = {};

    // prologue: stage tile 0, wait (syncthreads drains vmcnt(0))
    STAGE(0, 0);
    __syncthreads();

    int cur = 0;
    for (int kt = 0; kt < 8; ++kt) {
        if (kt < 7) STAGE(kt + 1, cur ^ 1);    // issue next-tile loads FIRST
#pragma unroll
        for (int ks = 0; ks < 2; ++ks) {
            const int g = ks * 4 + (lane >> 4);          // chunk index 0..7
            const int cswz = (g ^ (lane & 7)) * 8;       // swizzled read off
            half8v a[4], b[4];
#pragma unroll
            for (int i = 0; i < 4; ++i)
                a[i] = *(const half8v*)(&Alds[cur][
                        (size_t)(wr * 64 + i * 16 + (lane & 15)) * 64 + cswz]);
#pragma unroll
            for (int j = 0; j < 4; ++j)
                b[j] = *(const half8v*)(&Blds[cur][
                        (size_t)(wc * 64 + j * 16 + (lane & 15)) * 64 + cswz]);
#pragma unroll
            for (int i = 0; i < 4; ++i)
#pragma unroll
                for (int j = 0; j < 4; ++j)
                    acc[i][j] = __builtin_amdgcn_mfma_f32_16x16x32_f16(
                        a[i], b[j], acc[i][j], 0, 0, 0);
        }
        __syncthreads();   // drains vmcnt(0): next buffer staged + LDS reads done
        cur ^= 1;
    }

    // epilogue: C/D layout col=lane&15, row=(lane>>4)*4+reg  [m89-verified]
    const int cr = (lane >> 4) * 4;
    const int cc0 = lane & 15;
    if (MODE == 0) {
        float* C = (float*)((wz == 0) ? O0 : (wz == 1) ? O1 : O2);
#pragma unroll
        for (int j = 0; j < 4; ++j) {
            const int col = n0 + wc * 64 + j * 16 + cc0;
            const float bv = bias[col];
#pragma unroll
            for (int i = 0; i < 4; ++i) {
                const size_t rbase = (size_t)(m0 + wr * 64 + i * 16 + cr);
#pragma unroll
                for (int rg = 0; rg < 4; ++rg)
                    C[(rbase + rg) * DD + col] = acc[i][j][rg] + bv;
            }
        }
    } else if (wz < 2) {
        // Q/K: fp16 row-major [row][512]
        _Float16* C = (_Float16*)((wz == 0) ? O0 : O1);
#pragma unroll
        for (int j = 0; j < 4; ++j) {
            const int col = n0 + wc * 64 + j * 16 + cc0;
            const float bv = bias[col];
#pragma unroll
            for (int i = 0; i < 4; ++i) {
                const size_t rbase = (size_t)(m0 + wr * 64 + i * 16 + cr);
#pragma unroll
                for (int rg = 0; rg < 4; ++rg)
                    C[(rbase + rg) * DD + col] = (_Float16)(acc[i][j][rg] + bv);
            }
        }
    } else {
        // V: fp16, transposed per head: Vt[((bn*8+h)*64+d)*128 + t]
        _Float16* Vt = (_Float16*)O2;
        const int bnq = m0 >> 7;       // one m-tile == one bn (TT == 128)
#pragma unroll
        for (int j = 0; j < 4; ++j) {
            const int col = n0 + wc * 64 + j * 16 + cc0;
            const int hh = col >> 6, d = col & 63;
            const float bv = bias[col];
#pragma unroll
            for (int i = 0; i < 4; ++i) {
                const int t0 = wr * 64 + i * 16 + cr;   // multiple of 4
                Hbits e0, e1, e2, e3;
                e0.f = (_Float16)(acc[i][j][0] + bv);
                e1.f = (_Float16)(acc[i][j][1] + bv);
                e2.f = (_Float16)(acc[i][j][2] + bv);
                e3.f = (_Float16)(acc[i][j][3] + bv);
                *(ushort4*)(Vt + ((size_t)(bnq * 8 + hh) * 64 + d) * 128 + t0)
                    = make_ushort4(e0.u, e1.u, e2.u, e3.u);
            }
        }
    }
}

// ---------------------------------------------------------------------------
// attn_mfma: one block per (bn,h), 4 waves x 32 q-rows, all-fp16 MFMA.
// (unchanged from R6/R10 — passed at absmax 0.0078)
// ---------------------------------------------------------------------------
__global__ __launch_bounds__(256)
void attn_mfma(const _Float16* __restrict__ Qh, const _Float16* __restrict__ Kh,
               const _Float16* __restrict__ Vt, const float* __restrict__ mask,
               _Float16* __restrict__ Oh) {
    __shared__ _Float16 KP[128 * 128];    // K rows [128][64]; later P [128][128]
    __shared__ _Float16 Vl[64 * 128];     // V^T rows
    __shared__ float maskS[TT];

    const int bnh = blockIdx.x, bn = bnh >> 3, h = bnh & 7;
    const int tid = threadIdx.x, lane = tid & 63, wid = tid >> 6;
    const int l15 = lane & 15, l16 = lane >> 4;

    if (tid < TT) maskS[tid] = mask[bn * TT + tid];

    // stage K: 128 rows x 8 chunks (16B), source-swizzled, LDS linear
#pragma unroll
    for (int it = 0; it < 4; ++it) {
        const int ubase = it * 256 + wid * 64;
        const int u = ubase + lane;
        const int row = u >> 3, c = u & 7;
        const _Float16* gp = Kh + (size_t)(bn * TT + row) * DD + h * DH +
                             (c ^ (row & 7)) * 8;
        __builtin_amdgcn_global_load_lds(
            (const AS1 void*)gp, (AS3 void*)(KP + ubase * 8), 16, 0, 0);
    }
    // stage V^T: 64 rows x 16 chunks
#pragma unroll
    for (int it = 0; it < 4; ++it) {
        const int ubase = it * 256 + wid * 64;
        const int u = ubase + lane;
        const int row = u >> 4, c = u & 15;
        const _Float16* gp = Vt + ((size_t)(bn * HH + h) * 64 + row) * 128 +
                             (c ^ (row & 15)) * 8;
        __builtin_amdgcn_global_load_lds(
            (const AS1 void*)gp, (AS3 void*)(Vl + ubase * 8), 16, 0, 0);
    }
    // Q fragments direct to registers: qf[i][ks]
    half8v qf[2][2];
#pragma unroll
    for (int i = 0; i < 2; ++i)
#pragma unroll
        for (int ks = 0; ks < 2; ++ks)
            qf[i][ks] = *(const half8v*)(Qh +
                (size_t)(bn * TT + wid * 32 + i * 16 + l15) * DD +
                h * DH + ks * 32 + l16 * 8);
    __syncthreads();

    // QK^T: S[q 32][kv 128] per wave; 32 MFMA
    float4v s[2][8] = {};
#pragma unroll
    for (int ks = 0; ks < 2; ++ks) {
#pragma unroll
        for (int j = 0; j < 8; ++j) {
            const int row = j * 16 + l15;            // row&7 == l15&7
            const int g = ks * 4 + l16;
            half8v bf = *(const half8v*)(KP + (size_t)row * 64 +
                                         ((g ^ (l15 & 7)) * 8));
            s[0][j] = __builtin_amdgcn_mfma_f32_16x16x32_f16(
                qf[0][ks], bf, s[0][j], 0, 0, 0);
            s[1][j] = __builtin_amdgcn_mfma_f32_16x16x32_f16(
                qf[1][ks], bf, s[1][j], 0, 0, 0);
        }
    }

    // masked softmax, in-register. S frag: row=l16*4+reg, col=l15+16j
    float lrow[2][4];
#pragma unroll
    for (int i = 0; i < 2; ++i) {
#pragma unroll
        for (int reg = 0; reg < 4; ++reg) {
            const int q = wid * 32 + i * 16 + l16 * 4 + reg;
            const float rv = maskS[q];
            float mx = -1e30f;
#pragma unroll
            for (int j = 0; j < 8; ++j) {
                const bool valid = (rv != 0.f) && (maskS[j * 16 + l15] != 0.f);
                const float sv = valid ? s[i][j][reg] * 0.125f : -1e30f;
                s[i][j][reg] = sv;
                mx = fmaxf(mx, sv);
            }
#pragma unroll
            for (int d = 1; d < 16; d <<= 1) mx = fmaxf(mx, __shfl_xor(mx, d));
            float ls = 0.f;
#pragma unroll
            for (int j = 0; j < 8; ++j) {
                const float sv = s[i][j][reg];
                const float pv = (sv > -1e29f) ? __expf(sv - mx) : 0.f;
                s[i][j][reg] = pv;
                ls += pv;
            }
#pragma unroll
            for (int d = 1; d < 16; d <<= 1) ls += __shfl_xor(ls, d);
            lrow[i][reg] = ls;
        }
    }

    __syncthreads();          // all waves done reading KP (as K)
    // write P (fp16) into KP [128 q][128 kv], chunk-swizzled for A reads
#pragma unroll
    for (int i = 0; i < 2; ++i)
#pragma unroll
        for (int j = 0; j < 8; ++j)
#pragma unroll
            for (int reg = 0; reg < 4; ++reg) {
                const int q = wid * 32 + i * 16 + l16 * 4 + reg;
                const int kv = j * 16 + l15;
                const int c = kv >> 3, o = kv & 7;
                KP[(size_t)q * 128 + ((c ^ (q & 15)) * 8 + o)] =
                    (_Float16)s[i][j][reg];
            }
    __syncthreads();

    // PV: out[q 32][d 64] per wave, K=128 over kv; 32 MFMA
    float4v o_[2][4] = {};
#pragma unroll
    for (int ks = 0; ks < 4; ++ks) {
        half8v a[2];
#pragma unroll
        for (int i = 0; i < 2; ++i) {
            const int row = wid * 32 + i * 16 + l15;   // row&15 == l15
            const int g = ks * 4 + l16;
            a[i] = *(const half8v*)(KP + (size_t)row * 128 + ((g ^ l15) * 8));
        }
#pragma unroll
        for (int j = 0; j < 4; ++j) {
            const int row = j * 16 + l15;              // d row; row&15 == l15
            const int g = ks * 4 + l16;
            half8v bv = *(const half8v*)(Vl + (size_t)row * 128 +
                                         ((g ^ l15) * 8));
#pragma unroll
            for (int i = 0; i < 2; ++i)
                o_[i][j] = __builtin_amdgcn_mfma_f32_16x16x32_f16(
                    a[i], bv, o_[i][j], 0, 0, 0);
        }
    }

    // normalize + fp16 store to Oh [row][512]
#pragma unroll
    for (int i = 0; i < 2; ++i)
#pragma unroll
        for (int reg = 0; reg < 4; ++reg) {
            const float l = lrow[i][reg];
            const float inv = (l > 0.f) ? 1.f / l : 0.f;  // zero invalid rows
            const size_t grow = (size_t)bn * TT + wid * 32 + i * 16 +
                                l16 * 4 + reg;
#pragma unroll
            for (int j = 0; j < 4; ++j) {
                const int d = j * 16 + l15;
                Oh[grow * DD + h * DH + d] = (_Float16)(o_[i][j][reg] * inv);
            }
        }
}

// ---------------------------------------------------------------------------
// kernel_launch
// inputs: x(0) mask(1) Wq(2) bq(3) Wk(4) bk(5) Wv(6) bv(7) Wo(8) bo(9)
//
// Workspace (322 MiB of the proven 512): Xh[64] | Qh[64] | Kh[64] | Vt[64] |
// Oh[64] | Wh0..3 [2 MiB]. All fp16.
// ---------------------------------------------------------------------------
extern "C" void kernel_launch(void* const* d_in, const int* in_sizes, int n_in,
                              void* d_out, int out_size, void* d_ws, size_t ws_size,
                              hipStream_t stream) {
    const float* x    = (const float*)d_in[0];
    const float* mask = (const float*)d_in[1];
    const float* Wq   = (const float*)d_in[2];
    const float* bq   = (const float*)d_in[3];
    const float* Wk   = (const float*)d_in[4];
    const float* bk   = (const float*)d_in[5];
    const float* Wv   = (const float*)d_in[6];
    const float* bv   = (const float*)d_in[7];
    const float* Wo   = (const float*)d_in[8];
    const float* bo   = (const float*)d_in[9];
    float* out = (float*)d_out;

    const size_t elems = (size_t)MTOT * DD;          // 33.5M halves per buffer
    _Float16* Xh  = (_Float16*)d_ws;
    _Float16* Qh  = Xh + elems;
    _Float16* Kh  = Qh + elems;
    _Float16* Vtb = Kh + elems;
    _Float16* Oh  = Vtb + elems;
    _Float16* Wh  = Oh + elems;                      // 4 x 512*512

    cvt_x<<<2048, 256, 0, stream>>>(x, Xh);
    cvt_w4<<<dim3(1024, 4), 256, 0, stream>>>(Wq, Wk, Wv, Wo, Wh);

    // QKV projections -> Qh/Kh fp16 row-major, Vt fp16 transposed per head
    // grid: mt-major 1D (bid = mt*12 + wz*4 + nt) for A-panel L2 locality
    gemm_mfma<1><<<512 * 12, 256, 0, stream>>>(
        Xh, Wh + 0 * (size_t)DD * DD, Wh + 1 * (size_t)DD * DD,
        Wh + 2 * (size_t)DD * DD, bq, bk, bv, Qh, Kh, Vtb);
    // fused masked attention (all-fp16 MFMA)
    attn_mfma<<<dim3(BN * HH), 256, 0, stream>>>(Qh, Kh, Vtb, mask, Oh);
    // output projection (fp32 out)
    gemm_mfma<0><<<512 * 4, 256, 0, stream>>>(
        Oh, Wh + 3 * (size_t)DD * DD, nullptr, nullptr, bo, bo, bo,
        out, out, out);
}